// Round 11
// baseline (120.899 us; speedup 1.0000x reference)
//
#include <hip/hip_runtime.h>
#include <hip/hip_cooperative_groups.h>
#include <math.h>

namespace cg = cooperative_groups;

// Problem constants
#define NB 256   // batches
#define NN 32    // agents
#define DD 128   // state dim
#define NA 16    // action dim
#define HH 256   // hidden

using f32x4v  = __attribute__((ext_vector_type(4))) float;
using bf16x8  = __attribute__((ext_vector_type(8))) short;

static __device__ __forceinline__ float4 ld4(const float* p){ return *reinterpret_cast<const float4*>(p); }
static __device__ __forceinline__ void st4f(float* p, float4 v){ *reinterpret_cast<float4*>(p) = v; }
static __device__ __forceinline__ float elem(float4 v, int kk){
    return (kk==0)?v.x:(kk==1)?v.y:(kk==2)?v.z:v.w;
}

static __device__ __forceinline__ unsigned f2bf(float x){
    unsigned u = __float_as_uint(x);
    u += 0x7fffu + ((u >> 16) & 1u);   // round-to-nearest-even
    return u >> 16;
}
static __device__ __forceinline__ unsigned pack2(float a, float b){
    return f2bf(a) | (f2bf(b) << 16);
}
static __device__ __forceinline__ float bf2f(unsigned short s){
    return __uint_as_float(((unsigned)s) << 16);
}

static __device__ __forceinline__ f32x4v mfma16(bf16x8 a, bf16x8 b, f32x4v c){
    return __builtin_amdgcn_mfma_f32_16x16x32_bf16(a, b, c, 0, 0, 0);
}

static __device__ __forceinline__ bf16x8 to_bf8(const float v[8]){
    union { bf16x8 v8; unsigned u[4]; } r;
    #pragma unroll
    for (int j = 0; j < 4; j++) r.u[j] = pack2(v[2*j], v[2*j+1]);
    return r.v8;
}

// write one B-fragment (16 bf16 bytes per lane) to the swizzled weight buffer
static __device__ __forceinline__ void store_frag(unsigned short* __restrict__ dst,
                                                  int frag, int l, const float v[8]){
    uint4 p;
    p.x = pack2(v[0], v[1]); p.y = pack2(v[2], v[3]);
    p.z = pack2(v[4], v[5]); p.w = pack2(v[6], v[7]);
    *reinterpret_cast<uint4*>(dst + (size_t)(frag*64 + l)*8) = p;
}

// scores+softmax, 512 threads: thread (i=t>>4, j=t&15) covers (i,j) and (i,j+16).
static __device__ __forceinline__ void scores_softmax512(const float* __restrict__ Qm,
                                                         const float* __restrict__ Km,
                                                         float scale,
                                                         float* __restrict__ w_lds,
                                                         float* __restrict__ w_out,
                                                         int i, int j)
{
    float s0 = 0.f, s1 = 0.f;
    #pragma unroll 4
    for (int k=0;k<128;k+=4){
        float4 qv = ld4(Qm + i*132 + k);
        float4 k0 = ld4(Km + j*132 + k);
        float4 k1 = ld4(Km + (j+16)*132 + k);
        s0 += qv.x*k0.x + qv.y*k0.y + qv.z*k0.z + qv.w*k0.w;
        s1 += qv.x*k1.x + qv.y*k1.y + qv.z*k1.z + qv.w*k1.w;
    }
    s0 *= scale; s1 *= scale;
    float m = fmaxf(s0, s1);
    #pragma unroll
    for (int d=1; d<16; d<<=1) m = fmaxf(m, __shfl_xor(m, d));
    float e0 = expf(s0 - m), e1 = expf(s1 - m);
    float sum = e0 + e1;
    #pragma unroll
    for (int d=1; d<16; d<<=1) sum += __shfl_xor(sum, d);
    float inv = 1.f / sum;
    e0 *= inv; e1 *= inv;
    w_lds[i*36 + j]      = e0;
    w_lds[i*36 + j + 16] = e1;
    w_out[i*32 + j]      = e0;
    w_out[i*32 + j + 16] = e1;
}

// =============================================================================
// k_fused: single cooperative launch, grid 256 x 512.
//   PRE  (blocks 0..35): WAB = We@(Wav@W1) via MFMA (blocks 0..15, one 16-col
//         tile each) + fragment-swizzled bf16 copies of the 5 attention
//         weights (blocks 16..35). __threadfence + grid.sync() hand off.
//   MAIN (all 256 blocks): one batch per block, R10 body.
// Fragment layout (16x16x32 B-frag): frag (kt,nt): lane l holds
//   B[kt*32+(l>>4)*8+i][nt*16+(l&15)], i=0..7.
// =============================================================================
__global__ __launch_bounds__(512)
void k_fused(const float* __restrict__ states, const float* __restrict__ pol,
             const float* __restrict__ act,
             const float* __restrict__ Wkp, const float* __restrict__ Wqp,
             const float* __restrict__ Wvp, const float* __restrict__ Wk,
             const float* __restrict__ Wq,  const float* __restrict__ We,
             const float* __restrict__ Wav, const float* __restrict__ W1,
             const float* __restrict__ W2,
             float* __restrict__ out_v, float* __restrict__ out_w1,
             float* __restrict__ out_w2,
             float* __restrict__ WABf, unsigned short* __restrict__ WABs,
             unsigned short* __restrict__ Wqps, unsigned short* __restrict__ Wkps,
             unsigned short* __restrict__ Wvps, unsigned short* __restrict__ Wqs,
             unsigned short* __restrict__ Wks)
{
    __shared__ float SH[16000];   // 62.5 KB, shared by PRE and MAIN phases
    const int t = threadIdx.x;
    const int bid = blockIdx.x;

    // ========================= PRE phase =========================
    if (bid < 16) {
        float* T2f  = SH;          // [128][20] T2 col-slice fp32
        float* WABt = SH + 2560;   // [160][16] WAB col-tile fp32
        const int ct = bid;
        const int l  = t & 63, wvv = t >> 6;   // lane, wave
        const int lg = l >> 4;                 // k-subgroup 0..3
        const int lc = l & 15;                 // row/col within tile

        // ---- T2-stage: wave wvv owns M-tile wvv ----
        {
            const int arow = wvv*16 + lc;
            f32x4v acc = {0.f,0.f,0.f,0.f};
            #pragma unroll
            for (int kt = 0; kt < 4; kt++) {
                const float* ap = Wav + (size_t)arow*128 + kt*32 + lg*8;
                float4 a0 = ld4(ap), a1 = ld4(ap + 4);
                float av8[8] = {a0.x,a0.y,a0.z,a0.w,a1.x,a1.y,a1.z,a1.w};
                const float* bp = W1 + (size_t)(kt*32 + lg*8)*256 + ct*16 + lc;
                float bv8[8];
                #pragma unroll
                for (int i = 0; i < 8; i++) bv8[i] = bp[(size_t)i*256];
                acc = mfma16(to_bf8(av8), to_bf8(bv8), acc);
            }
            const int dr = wvv*16 + lg*4;
            #pragma unroll
            for (int r = 0; r < 4; r++) T2f[(dr+r)*20 + lc] = acc[r];
        }
        __syncthreads();

        // ---- WAB-stage: M-tiles 0..9 ----
        #pragma unroll
        for (int pass = 0; pass < 2; pass++) {
            const int mt = (pass == 0) ? wvv : 8 + wvv;
            if (pass == 1 && wvv >= 2) continue;
            const int arow = mt*16 + lc;
            f32x4v acc = {0.f,0.f,0.f,0.f};
            #pragma unroll
            for (int kt = 0; kt < 4; kt++) {
                float av8[8];
                if (arow < 144) {
                    const float* ap = We + (size_t)arow*128 + kt*32 + lg*8;
                    float4 a0 = ld4(ap), a1 = ld4(ap + 4);
                    av8[0]=a0.x; av8[1]=a0.y; av8[2]=a0.z; av8[3]=a0.w;
                    av8[4]=a1.x; av8[5]=a1.y; av8[6]=a1.z; av8[7]=a1.w;
                } else {
                    #pragma unroll
                    for (int i = 0; i < 8; i++) av8[i] = 0.f;
                }
                float bv8[8];
                #pragma unroll
                for (int i = 0; i < 8; i++) bv8[i] = T2f[(kt*32 + lg*8 + i)*20 + lc];
                acc = mfma16(to_bf8(av8), to_bf8(bv8), acc);
            }
            const int dr = mt*16 + lg*4;
            #pragma unroll
            for (int r = 0; r < 4; r++) WABt[(dr+r)*16 + lc] = acc[r];
            if (mt == 8) {
                #pragma unroll
                for (int r = 0; r < 4; r++)
                    WABf[(size_t)(dr+r)*256 + ct*16 + lc] = acc[r];
            }
        }
        __syncthreads();

        // ---- swizzle-emit 5 frags (kt=0..4, nt=ct) ----
        if (t < 320) {
            int kt = t >> 6, ll = t & 63;
            float v[8];
            #pragma unroll
            for (int i = 0; i < 8; i++)
                v[i] = WABt[(kt*32 + (ll>>4)*8 + i)*16 + (ll&15)];
            store_frag(WABs, kt*16 + ct, ll, v);
        }
    } else if (bid < 36) {
        // 8 frags per block; 160 frags = 5 weights x 32
        const int bb = bid - 16;
        const int fg = bb*8 + (t >> 6);
        const int l  = t & 63;
        const int sel = fg >> 5, frag = fg & 31;
        const int kt = frag >> 3, nt = frag & 7;
        const float* W = (sel==0) ? Wqp : (sel==1) ? Wkp : (sel==2) ? Wvp :
                         (sel==3) ? Wq : Wk;
        unsigned short* dst = (sel==0) ? Wqps : (sel==1) ? Wkps : (sel==2) ? Wvps :
                              (sel==3) ? Wqs : Wks;
        float v[8];
        #pragma unroll
        for (int i = 0; i < 8; i++)
            v[i] = W[(kt*32 + (l>>4)*8 + i)*128 + nt*16 + (l&15)];
        store_frag(dst, frag, l, v);
    }

    __threadfence();           // device-scope release of WABf/WABs/weight frags
    cg::this_grid().sync();    // all blocks see PRE results

    // ========================= MAIN phase =========================
    const int b = bid;
    const float scale = 0.08838834764831845f;  // 1/sqrt(128)

    float* B1   = SH;                                   // 32x132
    float* B2   = SH + 4224;                            // 32x132
    float* Wb2f = SH + 8448;                            // 32x36
    float* Wb1f = SH + 9600;                            // 32x36
    float* APd  = SH + 10752;                           // 32x16 (pol-act)
    unsigned short* Xoa  = (unsigned short*)(SH + 11264); // [32][168] bf16 (st|act|0)
    unsigned short* Ubf  = (unsigned short*)B1;           // [32][136] bf16
    unsigned short* Wvbf = (unsigned short*)B2;           // [32][136] bf16
    float*    A1 = SH;                                   // [32][260] fp32 (over B1+B2)
    unsigned* P2 = (unsigned*)(SH + 11904);              // [32][128] packed bf16 (over dead Xoa)
    unsigned* Q2 = (unsigned*)SH;                        // [32][132] packed bf16 (over dead A1)
    float* SPQ = Wb1f;   // SP[32][2] at 0, SQ[32][2] at +64 (Wb1f dead after P3)

    const float* stg  = states + (size_t)b*(NN*DD);
    const float* actg = act + (size_t)b*(NN*NA);
    const float* polg = pol + (size_t)b*(NN*NA);

    // ---- stage Xoa = bf16([st | act | 0]) (k 0..159), APd = pol-act ----
    {
        int r = t >> 4, kb = t & 15;
        #pragma unroll
        for (int uu = 0; uu < 10; uu++){
            int k = kb + 16*uu;
            float v = (k < 128) ? stg[r*128 + k]
                    : (k < 144) ? actg[r*16 + (k-128)] : 0.f;
            Xoa[r*168 + k] = (unsigned short)f2bf(v);
        }
        if (t < 128) {
            int rr = t>>2, cc = (t&3)*4;
            float4 p = ld4(polg + rr*16 + cc), a = ld4(actg + rr*16 + cc);
            st4f(APd + rr*16 + cc, make_float4(p.x-a.x, p.y-a.y, p.z-a.z, p.w-a.w));
        }
    }
    __syncthreads();

    // MFMA wave geometry
    const int l    = t & 63;
    const int wv   = t >> 6;             // wave 0..7
    const int mt   = wv & 1;             // M-tile
    const int ntb  = (wv >> 1) * 2;      // N-tile base (128-col GEMMs)
    const int nb7  = (wv >> 1) * 4;      // N-tile base (256-col GEMM)
    const int arow = mt*16 + (l & 15);
    const int drow = mt*16 + ((l >> 4) << 2);
    const int dcol = l & 15;

    // VALU phase geometry
    const int c  = t & 127;
    const int g  = t >> 7;
    const int cp = (t & 127)*2;
    const int si = t >> 4;
    const int sj = t & 15;
    const int wp = wv & 1;

    // ---- P1 (MFMA dual): q1 = st@Wqp -> B1, k1 = st@Wkp -> B2 ----
    {
        f32x4v aq0={0.f,0.f,0.f,0.f}, aq1={0.f,0.f,0.f,0.f};
        f32x4v ak0={0.f,0.f,0.f,0.f}, ak1={0.f,0.f,0.f,0.f};
        const unsigned short* ab = Xoa + arow*168 + (l>>4)*8;
        #pragma unroll
        for (int kt = 0; kt < 4; kt++){
            bf16x8 a   = *reinterpret_cast<const bf16x8*>(ab + kt*32);
            bf16x8 bq0 = *reinterpret_cast<const bf16x8*>(Wqps + (size_t)((kt*8+ntb  )*64 + l)*8);
            bf16x8 bq1 = *reinterpret_cast<const bf16x8*>(Wqps + (size_t)((kt*8+ntb+1)*64 + l)*8);
            bf16x8 bk0 = *reinterpret_cast<const bf16x8*>(Wkps + (size_t)((kt*8+ntb  )*64 + l)*8);
            bf16x8 bk1 = *reinterpret_cast<const bf16x8*>(Wkps + (size_t)((kt*8+ntb+1)*64 + l)*8);
            aq0 = mfma16(a, bq0, aq0); aq1 = mfma16(a, bq1, aq1);
            ak0 = mfma16(a, bk0, ak0); ak1 = mfma16(a, bk1, ak1);
        }
        #pragma unroll
        for (int r = 0; r < 4; r++){
            B1[(drow+r)*132 + ntb*16     + dcol] = aq0[r];
            B1[(drow+r)*132 + (ntb+1)*16 + dcol] = aq1[r];
            B2[(drow+r)*132 + ntb*16     + dcol] = ak0[r];
            B2[(drow+r)*132 + (ntb+1)*16 + dcol] = ak1[r];
        }
    }
    __syncthreads();

    // ---- P2: w1 = softmax(q1@k1^T * scale) ----
    scores_softmax512(B1, B2, scale, Wb1f, out_w1 + (size_t)b*1024, si, sj);
    __syncthreads();

    // ---- P3 (VALU): u = w1@st -> Ubf (bf16, over B1) ----
    {
        float au[8];
        #pragma unroll
        for (int u=0;u<8;u++) au[u]=0.f;
        #pragma unroll
        for (int k0=0;k0<32;k0+=4){
            float4 xv[8];
            #pragma unroll
            for (int u=0;u<8;u++) xv[u] = ld4(Wb1f + (g*8+u)*36 + k0);
            #pragma unroll
            for (int kk=0;kk<4;kk++){
                float w = bf2f(Xoa[(k0+kk)*168 + c]);
                #pragma unroll
                for (int u=0;u<8;u++) au[u] = fmaf(elem(xv[u],kk), w, au[u]);
            }
        }
        __syncthreads();   // B1/scores traffic done before bf16 overwrite
        #pragma unroll
        for (int u=0;u<8;u++) Ubf[(g*8+u)*136 + c] = (unsigned short)f2bf(au[u]);
    }
    __syncthreads();

    // ---- P4 (MFMA): wav1 = u@Wvp -> Wvbf (bf16, over B2) ----
    {
        f32x4v av0={0.f,0.f,0.f,0.f}, av1={0.f,0.f,0.f,0.f};
        const unsigned short* ab = Ubf + arow*136 + (l>>4)*8;
        #pragma unroll
        for (int kt = 0; kt < 4; kt++){
            bf16x8 a  = *reinterpret_cast<const bf16x8*>(ab + kt*32);
            bf16x8 b0 = *reinterpret_cast<const bf16x8*>(Wvps + (size_t)((kt*8+ntb  )*64 + l)*8);
            bf16x8 b1 = *reinterpret_cast<const bf16x8*>(Wvps + (size_t)((kt*8+ntb+1)*64 + l)*8);
            av0 = mfma16(a, b0, av0); av1 = mfma16(a, b1, av1);
        }
        #pragma unroll
        for (int r = 0; r < 4; r++){
            Wvbf[(drow+r)*136 + ntb*16     + dcol] = (unsigned short)f2bf(av0[r]);
            Wvbf[(drow+r)*136 + (ntb+1)*16 + dcol] = (unsigned short)f2bf(av1[r]);
        }
    }
    __syncthreads();

    // ---- P5 (MFMA dual): q2 = wav1@Wq, k2 = wav1@Wk -> regs -> B1,B2 ----
    {
        f32x4v aq0={0.f,0.f,0.f,0.f}, aq1={0.f,0.f,0.f,0.f};
        f32x4v ak0={0.f,0.f,0.f,0.f}, ak1={0.f,0.f,0.f,0.f};
        const unsigned short* ab = Wvbf + arow*136 + (l>>4)*8;
        #pragma unroll
        for (int kt = 0; kt < 4; kt++){
            bf16x8 a   = *reinterpret_cast<const bf16x8*>(ab + kt*32);
            bf16x8 bq0 = *reinterpret_cast<const bf16x8*>(Wqs + (size_t)((kt*8+ntb  )*64 + l)*8);
            bf16x8 bq1 = *reinterpret_cast<const bf16x8*>(Wqs + (size_t)((kt*8+ntb+1)*64 + l)*8);
            bf16x8 bk0 = *reinterpret_cast<const bf16x8*>(Wks + (size_t)((kt*8+ntb  )*64 + l)*8);
            bf16x8 bk1 = *reinterpret_cast<const bf16x8*>(Wks + (size_t)((kt*8+ntb+1)*64 + l)*8);
            aq0 = mfma16(a, bq0, aq0); aq1 = mfma16(a, bq1, aq1);
            ak0 = mfma16(a, bk0, ak0); ak1 = mfma16(a, bk1, ak1);
        }
        __syncthreads();   // everyone done reading Wvbf
        #pragma unroll
        for (int r = 0; r < 4; r++){
            B1[(drow+r)*132 + ntb*16     + dcol] = aq0[r];
            B1[(drow+r)*132 + (ntb+1)*16 + dcol] = aq1[r];
            B2[(drow+r)*132 + ntb*16     + dcol] = ak0[r];
            B2[(drow+r)*132 + (ntb+1)*16 + dcol] = ak1[r];
        }
    }
    __syncthreads();

    // ---- P6: w2 = softmax(q2@k2^T * scale) ----
    scores_softmax512(B1, B2, scale, Wb2f, out_w2 + (size_t)b*1024, si, sj);
    __syncthreads();

    // ---- P7 (MFMA): A1 = [st|act|0]@WAB (K=160, N=256) -> A1 (over B1/B2) ----
    {
        f32x4v ac[4];
        #pragma unroll
        for (int n=0;n<4;n++) ac[n] = f32x4v{0.f,0.f,0.f,0.f};
        const unsigned short* ab = Xoa + arow*168 + (l>>4)*8;
        #pragma unroll
        for (int kt = 0; kt < 5; kt++){
            bf16x8 a = *reinterpret_cast<const bf16x8*>(ab + kt*32);
            #pragma unroll
            for (int n = 0; n < 4; n++){
                bf16x8 bb = *reinterpret_cast<const bf16x8*>(WABs + (size_t)((kt*16 + nb7 + n)*64 + l)*8);
                ac[n] = mfma16(a, bb, ac[n]);
            }
        }
        #pragma unroll
        for (int n = 0; n < 4; n++){
            #pragma unroll
            for (int r = 0; r < 4; r++)
                A1[(drow+r)*260 + (nb7+n)*16 + dcol] = ac[n][r];
        }
    }
    __syncthreads();

    // ---- P8 (VALU): P = w2@A1 (K=32) -> bf16 P2 (over dead Xoa) + SP ----
    {
        float ap0[8], ap1[8];
        #pragma unroll
        for (int u=0;u<8;u++){ ap0[u]=0.f; ap1[u]=0.f; }
        #pragma unroll
        for (int k0=0;k0<32;k0+=4){
            float4 xv[8];
            #pragma unroll
            for (int u=0;u<8;u++) xv[u] = ld4(Wb2f + (g*8+u)*36 + k0);
            #pragma unroll
            for (int kk=0;kk<4;kk++){
                float2 w = *reinterpret_cast<const float2*>(A1 + (k0+kk)*260 + cp);
                #pragma unroll
                for (int u=0;u<8;u++){
                    float x = elem(xv[u],kk);
                    ap0[u] = fmaf(x, w.x, ap0[u]);
                    ap1[u] = fmaf(x, w.y, ap1[u]);
                }
            }
        }
        __syncthreads();  // A1/Xoa reads done before P2 overwrite
        #pragma unroll
        for (int u=0;u<8;u++)
            P2[(g*8+u)*128 + (cp>>1)] = pack2(ap0[u], ap1[u]);
        // SP[row] = sum_h W2[h]*P[row][h]: per-lane partial + wave butterfly
        float2 w2v = *reinterpret_cast<const float2*>(W2 + cp);
        float sp[8];
        #pragma unroll
        for (int u=0;u<8;u++) sp[u] = ap0[u]*w2v.x + ap1[u]*w2v.y;
        #pragma unroll
        for (int d=1; d<64; d<<=1){
            #pragma unroll
            for (int u=0;u<8;u++) sp[u] += __shfl_xor(sp[u], d);
        }
        if (l == 0){
            #pragma unroll
            for (int u=0;u<8;u++) SPQ[(g*8+u)*2 + wp] = sp[u];
        }
    }
    __syncthreads();

    // ---- P9 (VALU): Q = (pol-act)@WB (K=16) -> bf16 Q2 (over dead A1) + SQ ----
    {
        float aq0[8], aq1[8];
        #pragma unroll
        for (int u=0;u<8;u++){ aq0[u]=0.f; aq1[u]=0.f; }
        const float* wB = WABf + 128*256;
        #pragma unroll
        for (int k0=0;k0<16;k0+=4){
            float4 xv[8];
            #pragma unroll
            for (int u=0;u<8;u++) xv[u] = ld4(APd + (g*8+u)*16 + k0);
            #pragma unroll
            for (int kk=0;kk<4;kk++){
                float2 w = *reinterpret_cast<const float2*>(wB + (k0+kk)*256 + cp);
                #pragma unroll
                for (int u=0;u<8;u++){
                    float x = elem(xv[u],kk);
                    aq0[u] = fmaf(x, w.x, aq0[u]);
                    aq1[u] = fmaf(x, w.y, aq1[u]);
                }
            }
        }
        #pragma unroll
        for (int u=0;u<8;u++)
            Q2[(g*8+u)*132 + (cp>>1)] = pack2(aq0[u], aq1[u]);
        float2 w2v = *reinterpret_cast<const float2*>(W2 + cp);
        float sq[8];
        #pragma unroll
        for (int u=0;u<8;u++) sq[u] = aq0[u]*w2v.x + aq1[u]*w2v.y;
        #pragma unroll
        for (int d=1; d<64; d<<=1){
            #pragma unroll
            for (int u=0;u<8;u++) sq[u] += __shfl_xor(sq[u], d);
        }
        if (l == 0){
            #pragma unroll
            for (int u=0;u<8;u++) SPQ[64 + (g*8+u)*2 + wp] = sq[u];
        }
    }
    __syncthreads();

    // ---- P10: value[i,j] = 0.505*(SP[i]+w*SQ[j]) + 0.495*sum_h W2[h]*|..| ----
    {
        float w00 = Wb2f[si*36 + sj], w01 = Wb2f[si*36 + sj + 16];
        float SPi = SPQ[si*2] + SPQ[si*2+1];
        float SQa = SPQ[64 + sj*2] + SPQ[64 + sj*2+1];
        float SQb = SPQ[64 + (sj+16)*2] + SPQ[64 + (sj+16)*2+1];
        float a0 = 0.f, a1 = 0.f;

        #define PROC(PA,QA,QB,H2) {                                         \
            float w2e = W2[(H2)], w2o = W2[(H2)+1];                         \
            float paE = __uint_as_float((PA)<<16), paO = __uint_as_float((PA) & 0xffff0000u); \
            float qaE = __uint_as_float((QA)<<16), qaO = __uint_as_float((QA) & 0xffff0000u); \
            float qbE = __uint_as_float((QB)<<16), qbO = __uint_as_float((QB) & 0xffff0000u); \
            float t0 = fmaf(w00, qaE, paE); a0 = fmaf(fabsf(t0), w2e, a0);  \
            float t1 = fmaf(w00, qaO, paO); a0 = fmaf(fabsf(t1), w2o, a0);  \
            float t2 = fmaf(w01, qbE, paE); a1 = fmaf(fabsf(t2), w2e, a1);  \
            float t3 = fmaf(w01, qbO, paO); a1 = fmaf(fabsf(t3), w2o, a1); }

        #pragma unroll 4
        for (int hp4 = 0; hp4 < 32; hp4++){
            uint4 pa4 = *reinterpret_cast<const uint4*>(P2 + si*128 + hp4*4);
            uint4 qa4 = *reinterpret_cast<const uint4*>(Q2 + sj*132 + hp4*4);
            uint4 qb4 = *reinterpret_cast<const uint4*>(Q2 + (sj+16)*132 + hp4*4);
            PROC(pa4.x, qa4.x, qb4.x, hp4*8+0)
            PROC(pa4.y, qa4.y, qb4.y, hp4*8+2)
            PROC(pa4.z, qa4.z, qb4.z, hp4*8+4)
            PROC(pa4.w, qa4.w, qb4.w, hp4*8+6)
        }
        #undef PROC

        float* ov = out_v + (size_t)b*1024;
        ov[si*32 + sj]      = fmaf(0.495f, a0, 0.505f*(SPi + w00*SQa));
        ov[si*32 + sj + 16] = fmaf(0.495f, a1, 0.505f*(SPi + w01*SQb));
    }
}

extern "C" void kernel_launch(void* const* d_in, const int* in_sizes, int n_in,
                              void* d_out, int out_size, void* d_ws, size_t ws_size,
                              hipStream_t stream) {
    const float* states = (const float*)d_in[0];
    const float* pol    = (const float*)d_in[1];
    const float* act    = (const float*)d_in[2];
    const float* Wkp    = (const float*)d_in[3];
    const float* Wqp    = (const float*)d_in[4];
    const float* Wvp    = (const float*)d_in[5];
    const float* Wk     = (const float*)d_in[6];
    const float* Wq     = (const float*)d_in[7];
    const float* We     = (const float*)d_in[8];
    const float* Wav    = (const float*)d_in[9];
    const float* W1     = (const float*)d_in[10];
    const float* W2     = (const float*)d_in[11];

    float* out    = (float*)d_out;
    float* out_v  = out;                 // [256,32,32,1]
    float* out_w1 = out + 256*1024;      // [256,32,32]
    float* out_w2 = out + 2*256*1024;    // [256,32,32]

    // workspace layout (floats)
    float* WABf = (float*)d_ws;                                  // [144][256] fp32 (rows 128..143 used)
    unsigned short* WABs = (unsigned short*)(WABf + 36864);      // 80 frags * 512 = 40960 ush
    unsigned short* wsu  = (unsigned short*)(WABf + 57344);
    unsigned short* Wqps = wsu;             // 32 frags * 512 = 16384 ush each
    unsigned short* Wkps = wsu + 16384;
    unsigned short* Wvps = wsu + 32768;
    unsigned short* Wqs  = wsu + 49152;
    unsigned short* Wks  = wsu + 65536;

    void* kargs[] = {
        (void*)&states, (void*)&pol, (void*)&act,
        (void*)&Wkp, (void*)&Wqp, (void*)&Wvp, (void*)&Wk, (void*)&Wq,
        (void*)&We, (void*)&Wav, (void*)&W1, (void*)&W2,
        (void*)&out_v, (void*)&out_w1, (void*)&out_w2,
        (void*)&WABf, (void*)&WABs,
        (void*)&Wqps, (void*)&Wkps, (void*)&Wvps, (void*)&Wqs, (void*)&Wks
    };
    hipLaunchCooperativeKernel((const void*)k_fused, dim3(NB), dim3(512),
                               kargs, 0, stream);
}

// Round 12
// 41.870 us; speedup vs baseline: 2.8875x; 2.8875x over previous
//
#include <hip/hip_runtime.h>
#include <math.h>

// Problem constants
#define NB 256   // batches
#define NN 32    // agents
#define DD 128   // state dim
#define NA 16    // action dim
#define HH 256   // hidden
#define NPRE 40
#define MAGIC 0x5AFEC0DE5AFEC0DEULL

using f32x4v  = __attribute__((ext_vector_type(4))) float;
using bf16x8  = __attribute__((ext_vector_type(8))) short;

static __device__ __forceinline__ float4 ld4(const float* p){ return *reinterpret_cast<const float4*>(p); }
static __device__ __forceinline__ void st4f(float* p, float4 v){ *reinterpret_cast<float4*>(p) = v; }
static __device__ __forceinline__ float elem(float4 v, int kk){
    return (kk==0)?v.x:(kk==1)?v.y:(kk==2)?v.z:v.w;
}

static __device__ __forceinline__ unsigned f2bf(float x){
    unsigned u = __float_as_uint(x);
    u += 0x7fffu + ((u >> 16) & 1u);   // round-to-nearest-even
    return u >> 16;
}
static __device__ __forceinline__ unsigned pack2(float a, float b){
    return f2bf(a) | (f2bf(b) << 16);
}
static __device__ __forceinline__ float bf2f(unsigned short s){
    return __uint_as_float(((unsigned)s) << 16);
}

static __device__ __forceinline__ f32x4v mfma16(bf16x8 a, bf16x8 b, f32x4v c){
    return __builtin_amdgcn_mfma_f32_16x16x32_bf16(a, b, c, 0, 0, 0);
}

static __device__ __forceinline__ bf16x8 to_bf8(const float v[8]){
    union { bf16x8 v8; unsigned u[4]; } r;
    #pragma unroll
    for (int j = 0; j < 4; j++) r.u[j] = pack2(v[2*j], v[2*j+1]);
    return r.v8;
}

// write one B-fragment (16 bf16 bytes per lane) to the swizzled weight buffer
static __device__ __forceinline__ void store_frag(unsigned short* __restrict__ dst,
                                                  int frag, int l, const float v[8]){
    uint4 p;
    p.x = pack2(v[0], v[1]); p.y = pack2(v[2], v[3]);
    p.z = pack2(v[4], v[5]); p.w = pack2(v[6], v[7]);
    *reinterpret_cast<uint4*>(dst + (size_t)(frag*64 + l)*8) = p;
}

// scores+softmax, 512 threads: thread (i=t>>4, j=t&15) covers (i,j) and (i,j+16).
static __device__ __forceinline__ void scores_softmax512(const float* __restrict__ Qm,
                                                         const float* __restrict__ Km,
                                                         float scale,
                                                         float* __restrict__ w_lds,
                                                         float* __restrict__ w_out,
                                                         int i, int j)
{
    float s0 = 0.f, s1 = 0.f;
    #pragma unroll 4
    for (int k=0;k<128;k+=4){
        float4 qv = ld4(Qm + i*132 + k);
        float4 k0 = ld4(Km + j*132 + k);
        float4 k1 = ld4(Km + (j+16)*132 + k);
        s0 += qv.x*k0.x + qv.y*k0.y + qv.z*k0.z + qv.w*k0.w;
        s1 += qv.x*k1.x + qv.y*k1.y + qv.z*k1.z + qv.w*k1.w;
    }
    s0 *= scale; s1 *= scale;
    float m = fmaxf(s0, s1);
    #pragma unroll
    for (int d=1; d<16; d<<=1) m = fmaxf(m, __shfl_xor(m, d));
    float e0 = expf(s0 - m), e1 = expf(s1 - m);
    float sum = e0 + e1;
    #pragma unroll
    for (int d=1; d<16; d<<=1) sum += __shfl_xor(sum, d);
    float inv = 1.f / sum;
    e0 *= inv; e1 *= inv;
    w_lds[i*36 + j]      = e0;
    w_lds[i*36 + j + 16] = e1;
    w_out[i*32 + j]      = e0;
    w_out[i*32 + j + 16] = e1;
}

// =============================================================================
// k_all: single launch, 256 blocks x 512.
//  PRE (blocks 0..39):
//    0..15 : WAB col-tile (MFMA 2-stage, as R10) -> WABs frags + WABf rows
//    16..23: Wqp/Wkp fragment swizzles (8 frags each)
//    24..31: Wvq = Wvp@Wq col-tile ct (MFMA) -> Wvqs frags
//    32..39: Wvk = Wvp@Wk col-tile      -> Wvks frags
//    then threadfence + flag[bid]=MAGIC (agent scope).
//  MAIN (all blocks, batch b=bid): stage -> spin flags -> P1 (q1,k1,svq,svk MFMA;
//    svq/svk held in regs) -> sm1 -> svq/svk store -> q2,k2=w1@{svq,svk} (VALU)
//    -> sm2 -> A1 MFMA -> P=w2@A1 -> Q -> epilogue.
//  Replay-safe: pre results are input-deterministic; flags stay MAGIC across
//  replays so the race re-writes identical bytes.
// =============================================================================
__global__ __launch_bounds__(512)
void k_all(const float* __restrict__ states, const float* __restrict__ pol,
           const float* __restrict__ act,
           const float* __restrict__ Wkp, const float* __restrict__ Wqp,
           const float* __restrict__ Wvp, const float* __restrict__ Wk,
           const float* __restrict__ Wq,  const float* __restrict__ We,
           const float* __restrict__ Wav, const float* __restrict__ W1,
           const float* __restrict__ W2,
           float* __restrict__ out_v, float* __restrict__ out_w1,
           float* __restrict__ out_w2,
           float* __restrict__ WABf, unsigned short* __restrict__ WABs,
           unsigned short* __restrict__ Wqps, unsigned short* __restrict__ Wkps,
           unsigned short* __restrict__ Wvqs, unsigned short* __restrict__ Wvks,
           unsigned long long* __restrict__ flags)
{
    __shared__ float SH[15360];   // 60 KB
    const int t = threadIdx.x;
    const int bid = blockIdx.x;

    const int l   = t & 63;
    const int wvv = t >> 6;
    const int lg  = l >> 4;
    const int lc  = l & 15;

    // ========================= PRE =========================
    if (bid < NPRE) {
        if (bid < 16) {
            float* T2f  = SH;          // [128][20]
            float* WABt = SH + 2560;   // [160][16]
            const int ct = bid;
            // T2-stage: T2 = Wav @ W1[:,ct*16..)
            {
                const int arow = wvv*16 + lc;
                f32x4v acc = {0.f,0.f,0.f,0.f};
                #pragma unroll
                for (int kt = 0; kt < 4; kt++) {
                    const float* ap = Wav + (size_t)arow*128 + kt*32 + lg*8;
                    float4 a0 = ld4(ap), a1 = ld4(ap + 4);
                    float av8[8] = {a0.x,a0.y,a0.z,a0.w,a1.x,a1.y,a1.z,a1.w};
                    const float* bp = W1 + (size_t)(kt*32 + lg*8)*256 + ct*16 + lc;
                    float bv8[8];
                    #pragma unroll
                    for (int i = 0; i < 8; i++) bv8[i] = bp[(size_t)i*256];
                    acc = mfma16(to_bf8(av8), to_bf8(bv8), acc);
                }
                const int dr = wvv*16 + lg*4;
                #pragma unroll
                for (int r = 0; r < 4; r++) T2f[(dr+r)*20 + lc] = acc[r];
            }
            __syncthreads();
            // WAB-stage: We_pad @ T2 (M-tiles 0..9)
            #pragma unroll
            for (int pass = 0; pass < 2; pass++) {
                const int mt9 = (pass == 0) ? wvv : 8 + wvv;
                if (pass == 1 && wvv >= 2) continue;
                const int arow = mt9*16 + lc;
                f32x4v acc = {0.f,0.f,0.f,0.f};
                #pragma unroll
                for (int kt = 0; kt < 4; kt++) {
                    float av8[8];
                    if (arow < 144) {
                        const float* ap = We + (size_t)arow*128 + kt*32 + lg*8;
                        float4 a0 = ld4(ap), a1 = ld4(ap + 4);
                        av8[0]=a0.x; av8[1]=a0.y; av8[2]=a0.z; av8[3]=a0.w;
                        av8[4]=a1.x; av8[5]=a1.y; av8[6]=a1.z; av8[7]=a1.w;
                    } else {
                        #pragma unroll
                        for (int i = 0; i < 8; i++) av8[i] = 0.f;
                    }
                    float bv8[8];
                    #pragma unroll
                    for (int i = 0; i < 8; i++) bv8[i] = T2f[(kt*32 + lg*8 + i)*20 + lc];
                    acc = mfma16(to_bf8(av8), to_bf8(bv8), acc);
                }
                const int dr = mt9*16 + lg*4;
                #pragma unroll
                for (int r = 0; r < 4; r++) WABt[(dr+r)*16 + lc] = acc[r];
                if (mt9 == 8) {
                    #pragma unroll
                    for (int r = 0; r < 4; r++)
                        WABf[(size_t)(dr+r)*256 + ct*16 + lc] = acc[r];
                }
            }
            __syncthreads();
            if (t < 320) {
                int kt = t >> 6, ll = t & 63;
                float v[8];
                #pragma unroll
                for (int i = 0; i < 8; i++)
                    v[i] = WABt[(kt*32 + (ll>>4)*8 + i)*16 + (ll&15)];
                store_frag(WABs, kt*16 + ct, ll, v);
            }
        } else if (bid < 24) {
            // Wqp/Wkp fragment swizzles: 8 frags/block over 64 total
            const int bb = bid - 16;
            const int fg = bb*8 + (t >> 6);
            const int sel = fg >> 5, frag = fg & 31;
            const int kt = frag >> 3, nt = frag & 7;
            const float* W = (sel==0) ? Wqp : Wkp;
            unsigned short* dst = (sel==0) ? Wqps : Wkps;
            float v[8];
            #pragma unroll
            for (int i = 0; i < 8; i++)
                v[i] = W[(kt*32 + (l>>4)*8 + i)*128 + nt*16 + (l&15)];
            store_frag(dst, frag, l, v);
        } else {
            // Wvq (24..31) / Wvk (32..39): col tile ct, M=128,N=16,K=128
            float* T2f = SH;    // [128][20]
            const int ct = (bid - 24) & 7;
            const float* Bsrc = (bid < 32) ? Wq : Wk;
            unsigned short* dst = (bid < 32) ? Wvqs : Wvks;
            {
                const int arow = wvv*16 + lc;
                f32x4v acc = {0.f,0.f,0.f,0.f};
                #pragma unroll
                for (int kt = 0; kt < 4; kt++) {
                    const float* ap = Wvp + (size_t)arow*128 + kt*32 + lg*8;
                    float4 a0 = ld4(ap), a1 = ld4(ap + 4);
                    float av8[8] = {a0.x,a0.y,a0.z,a0.w,a1.x,a1.y,a1.z,a1.w};
                    const float* bp = Bsrc + (size_t)(kt*32 + lg*8)*128 + ct*16 + lc;
                    float bv8[8];
                    #pragma unroll
                    for (int i = 0; i < 8; i++) bv8[i] = bp[(size_t)i*128];
                    acc = mfma16(to_bf8(av8), to_bf8(bv8), acc);
                }
                const int dr = wvv*16 + lg*4;
                #pragma unroll
                for (int r = 0; r < 4; r++) T2f[(dr+r)*20 + lc] = acc[r];
            }
            __syncthreads();
            if (t < 256) {
                int kt = t >> 6, ll = t & 63;
                float v[8];
                #pragma unroll
                for (int i = 0; i < 8; i++)
                    v[i] = T2f[(kt*32 + (ll>>4)*8 + i)*20 + (ll&15)];
                store_frag(dst, kt*8 + ct, ll, v);
            }
        }
        __syncthreads();
        if (t == 0) {
            __threadfence();   // agent-scope release: L2 writeback on gfx950
            __hip_atomic_store(&flags[bid], (unsigned long long)MAGIC,
                               __ATOMIC_RELEASE, __HIP_MEMORY_SCOPE_AGENT);
        }
    }

    // ========================= MAIN =========================
    const int b = bid;
    const float scale = 0.08838834764831845f;  // 1/sqrt(128)

    float* B1   = SH;                                     // [32][132]
    float* B2   = SH + 4224;                              // [32][132]
    float* Wb1f = SH + 8448;                              // [32][36]
    float* Wb2f = SH + 9600;                              // [32][36]
    float* APd  = SH + 10752;                             // [32][16]
    unsigned short* Xoa = (unsigned short*)(SH + 11264);  // [32][168] bf16
    float*    A1 = SH;                                    // [32][260] over B1+B2
    unsigned* P2 = (unsigned*)(SH + 11264);               // [32][128] over dead Xoa
    unsigned* Q2 = (unsigned*)SH;                         // [32][132] over dead A1
    float* SPQ = Wb1f;                                    // SP/SQ over dead Wb1f

    const float* stg  = states + (size_t)b*(NN*DD);
    const float* actg = act + (size_t)b*(NN*NA);
    const float* polg = pol + (size_t)b*(NN*NA);

    // ---- stage Xoa = bf16([st | act | 0]), APd = pol-act (overlaps PRE) ----
    {
        int r = t >> 4, kb = t & 15;
        #pragma unroll
        for (int uu = 0; uu < 10; uu++){
            int k = kb + 16*uu;
            float v = (k < 128) ? stg[r*128 + k]
                    : (k < 144) ? actg[r*16 + (k-128)] : 0.f;
            Xoa[r*168 + k] = (unsigned short)f2bf(v);
        }
        if (t < 128) {
            int rr = t>>2, cc = (t&3)*4;
            float4 p = ld4(polg + rr*16 + cc), a = ld4(actg + rr*16 + cc);
            st4f(APd + rr*16 + cc, make_float4(p.x-a.x, p.y-a.y, p.z-a.z, p.w-a.w));
        }
    }

    // ---- wait for PRE results (replay-invariant handoff) ----
    if (t < NPRE) {
        while (__hip_atomic_load(&flags[t], __ATOMIC_ACQUIRE,
                                 __HIP_MEMORY_SCOPE_AGENT) != (unsigned long long)MAGIC) {}
        __threadfence();   // acquire: invalidate stale L1/L2
    }
    __syncthreads();

    // geometry
    const int mt   = wvv & 1;
    const int ntb  = (wvv >> 1) * 2;
    const int nb7  = (wvv >> 1) * 4;
    const int arow = mt*16 + lc;
    const int drow = mt*16 + (lg << 2);
    const int dcol = lc;
    const int c  = t & 127;
    const int g  = t >> 7;
    const int cp = (t & 127)*2;
    const int si = t >> 4;
    const int sj = t & 15;
    const int wp = wvv & 1;

    // ---- P1 (MFMA x4): q1->B1, k1->B2, svq/svk -> regs ----
    f32x4v asq0={0.f,0.f,0.f,0.f}, asq1={0.f,0.f,0.f,0.f};
    f32x4v ask0={0.f,0.f,0.f,0.f}, ask1={0.f,0.f,0.f,0.f};
    {
        f32x4v aq0={0.f,0.f,0.f,0.f}, aq1={0.f,0.f,0.f,0.f};
        f32x4v ak0={0.f,0.f,0.f,0.f}, ak1={0.f,0.f,0.f,0.f};
        const unsigned short* ab = Xoa + arow*168 + lg*8;
        #pragma unroll
        for (int kt = 0; kt < 4; kt++){
            bf16x8 a = *reinterpret_cast<const bf16x8*>(ab + kt*32);
            bf16x8 bq0 = *reinterpret_cast<const bf16x8*>(Wqps + (size_t)((kt*8+ntb  )*64 + l)*8);
            bf16x8 bq1 = *reinterpret_cast<const bf16x8*>(Wqps + (size_t)((kt*8+ntb+1)*64 + l)*8);
            bf16x8 bk0 = *reinterpret_cast<const bf16x8*>(Wkps + (size_t)((kt*8+ntb  )*64 + l)*8);
            bf16x8 bk1 = *reinterpret_cast<const bf16x8*>(Wkps + (size_t)((kt*8+ntb+1)*64 + l)*8);
            bf16x8 bv0 = *reinterpret_cast<const bf16x8*>(Wvqs + (size_t)((kt*8+ntb  )*64 + l)*8);
            bf16x8 bv1 = *reinterpret_cast<const bf16x8*>(Wvqs + (size_t)((kt*8+ntb+1)*64 + l)*8);
            bf16x8 bw0 = *reinterpret_cast<const bf16x8*>(Wvks + (size_t)((kt*8+ntb  )*64 + l)*8);
            bf16x8 bw1 = *reinterpret_cast<const bf16x8*>(Wvks + (size_t)((kt*8+ntb+1)*64 + l)*8);
            aq0 = mfma16(a, bq0, aq0); aq1 = mfma16(a, bq1, aq1);
            ak0 = mfma16(a, bk0, ak0); ak1 = mfma16(a, bk1, ak1);
            asq0 = mfma16(a, bv0, asq0); asq1 = mfma16(a, bv1, asq1);
            ask0 = mfma16(a, bw0, ask0); ask1 = mfma16(a, bw1, ask1);
        }
        #pragma unroll
        for (int r = 0; r < 4; r++){
            B1[(drow+r)*132 + ntb*16     + dcol] = aq0[r];
            B1[(drow+r)*132 + (ntb+1)*16 + dcol] = aq1[r];
            B2[(drow+r)*132 + ntb*16     + dcol] = ak0[r];
            B2[(drow+r)*132 + (ntb+1)*16 + dcol] = ak1[r];
        }
    }
    __syncthreads();

    // ---- sm1: w1 = softmax(q1@k1^T * scale) ----
    scores_softmax512(B1, B2, scale, Wb1f, out_w1 + (size_t)b*1024, si, sj);
    __syncthreads();

    // ---- store svq/svk over dead q1/k1 ----
    #pragma unroll
    for (int r = 0; r < 4; r++){
        B1[(drow+r)*132 + ntb*16     + dcol] = asq0[r];
        B1[(drow+r)*132 + (ntb+1)*16 + dcol] = asq1[r];
        B2[(drow+r)*132 + ntb*16     + dcol] = ask0[r];
        B2[(drow+r)*132 + (ntb+1)*16 + dcol] = ask1[r];
    }
    __syncthreads();

    // ---- P3': q2 = w1@SVQ, k2 = w1@SVK (VALU K=32) -> regs -> B1,B2 ----
    {
        float q2a[8], k2a[8];
        #pragma unroll
        for (int u=0;u<8;u++){ q2a[u]=0.f; k2a[u]=0.f; }
        #pragma unroll
        for (int k0=0;k0<32;k0+=4){
            float4 xv[8];
            #pragma unroll
            for (int u=0;u<8;u++) xv[u] = ld4(Wb1f + (g*8+u)*36 + k0);
            #pragma unroll
            for (int kk=0;kk<4;kk++){
                float vq = B1[(k0+kk)*132 + c];
                float vk = B2[(k0+kk)*132 + c];
                #pragma unroll
                for (int u=0;u<8;u++){
                    float x = elem(xv[u],kk);
                    q2a[u] = fmaf(x, vq, q2a[u]);
                    k2a[u] = fmaf(x, vk, k2a[u]);
                }
            }
        }
        __syncthreads();   // SVQ/SVK reads done
        #pragma unroll
        for (int u=0;u<8;u++){
            B1[(g*8+u)*132 + c] = q2a[u];
            B2[(g*8+u)*132 + c] = k2a[u];
        }
    }
    __syncthreads();

    // ---- sm2: w2 = softmax(q2@k2^T * scale) ----
    scores_softmax512(B1, B2, scale, Wb2f, out_w2 + (size_t)b*1024, si, sj);
    __syncthreads();

    // ---- P7 (MFMA): A1 = [st|act|0]@WAB (K=160,N=256) -> A1 (over B1/B2) ----
    {
        f32x4v ac[4];
        #pragma unroll
        for (int n=0;n<4;n++) ac[n] = f32x4v{0.f,0.f,0.f,0.f};
        const unsigned short* ab = Xoa + arow*168 + lg*8;
        #pragma unroll
        for (int kt = 0; kt < 5; kt++){
            bf16x8 a = *reinterpret_cast<const bf16x8*>(ab + kt*32);
            #pragma unroll
            for (int n = 0; n < 4; n++){
                bf16x8 bb = *reinterpret_cast<const bf16x8*>(WABs + (size_t)((kt*16 + nb7 + n)*64 + l)*8);
                ac[n] = mfma16(a, bb, ac[n]);
            }
        }
        #pragma unroll
        for (int n = 0; n < 4; n++){
            #pragma unroll
            for (int r = 0; r < 4; r++)
                A1[(drow+r)*260 + (nb7+n)*16 + dcol] = ac[n][r];
        }
    }
    __syncthreads();

    // ---- P8 (VALU): P = w2@A1 (K=32) -> bf16 P2 (over dead Xoa) + SP ----
    {
        float ap0[8], ap1[8];
        #pragma unroll
        for (int u=0;u<8;u++){ ap0[u]=0.f; ap1[u]=0.f; }
        #pragma unroll
        for (int k0=0;k0<32;k0+=4){
            float4 xv[8];
            #pragma unroll
            for (int u=0;u<8;u++) xv[u] = ld4(Wb2f + (g*8+u)*36 + k0);
            #pragma unroll
            for (int kk=0;kk<4;kk++){
                float2 w = *reinterpret_cast<const float2*>(A1 + (k0+kk)*260 + cp);
                #pragma unroll
                for (int u=0;u<8;u++){
                    float x = elem(xv[u],kk);
                    ap0[u] = fmaf(x, w.x, ap0[u]);
                    ap1[u] = fmaf(x, w.y, ap1[u]);
                }
            }
        }
        #pragma unroll
        for (int u=0;u<8;u++)
            P2[(g*8+u)*128 + (cp>>1)] = pack2(ap0[u], ap1[u]);
        float2 w2v = *reinterpret_cast<const float2*>(W2 + cp);
        float sp[8];
        #pragma unroll
        for (int u=0;u<8;u++) sp[u] = ap0[u]*w2v.x + ap1[u]*w2v.y;
        #pragma unroll
        for (int d=1; d<64; d<<=1){
            #pragma unroll
            for (int u=0;u<8;u++) sp[u] += __shfl_xor(sp[u], d);
        }
        if (l == 0){
            #pragma unroll
            for (int u=0;u<8;u++) SPQ[(g*8+u)*2 + wp] = sp[u];
        }
    }
    __syncthreads();

    // ---- P9 (VALU): Q = (pol-act)@WB -> bf16 Q2 (over dead A1) + SQ ----
    {
        float aq0[8], aq1[8];
        #pragma unroll
        for (int u=0;u<8;u++){ aq0[u]=0.f; aq1[u]=0.f; }
        const float* wB = WABf + 128*256;
        #pragma unroll
        for (int k0=0;k0<16;k0+=4){
            float4 xv[8];
            #pragma unroll
            for (int u=0;u<8;u++) xv[u] = ld4(APd + (g*8+u)*16 + k0);
            #pragma unroll
            for (int kk=0;kk<4;kk++){
                float2 w = *reinterpret_cast<const float2*>(wB + (k0+kk)*256 + cp);
                #pragma unroll
                for (int u=0;u<8;u++){
                    float x = elem(xv[u],kk);
                    aq0[u] = fmaf(x, w.x, aq0[u]);
                    aq1[u] = fmaf(x, w.y, aq1[u]);
                }
            }
        }
        #pragma unroll
        for (int u=0;u<8;u++)
            Q2[(g*8+u)*132 + (cp>>1)] = pack2(aq0[u], aq1[u]);
        float2 w2v = *reinterpret_cast<const float2*>(W2 + cp);
        float sq[8];
        #pragma unroll
        for (int u=0;u<8;u++) sq[u] = aq0[u]*w2v.x + aq1[u]*w2v.y;
        #pragma unroll
        for (int d=1; d<64; d<<=1){
            #pragma unroll
            for (int u=0;u<8;u++) sq[u] += __shfl_xor(sq[u], d);
        }
        if (l == 0){
            #pragma unroll
            for (int u=0;u<8;u++) SPQ[64 + (g*8+u)*2 + wp] = sq[u];
        }
    }
    __syncthreads();

    // ---- P10: value[i,j] = 0.505*(SP[i]+w*SQ[j]) + 0.495*sum_h W2[h]*|..| ----
    {
        float w00 = Wb2f[si*36 + sj], w01 = Wb2f[si*36 + sj + 16];
        float SPi = SPQ[si*2] + SPQ[si*2+1];
        float SQa = SPQ[64 + sj*2] + SPQ[64 + sj*2+1];
        float SQb = SPQ[64 + (sj+16)*2] + SPQ[64 + (sj+16)*2+1];
        float a0 = 0.f, a1 = 0.f;

        #define PROC(PA,QA,QB,H2) {                                         \
            float w2e = W2[(H2)], w2o = W2[(H2)+1];                         \
            float paE = __uint_as_float((PA)<<16), paO = __uint_as_float((PA) & 0xffff0000u); \
            float qaE = __uint_as_float((QA)<<16), qaO = __uint_as_float((QA) & 0xffff0000u); \
            float qbE = __uint_as_float((QB)<<16), qbO = __uint_as_float((QB) & 0xffff0000u); \
            float t0 = fmaf(w00, qaE, paE); a0 = fmaf(fabsf(t0), w2e, a0);  \
            float t1 = fmaf(w00, qaO, paO); a0 = fmaf(fabsf(t1), w2o, a0);  \
            float t2 = fmaf(w01, qbE, paE); a1 = fmaf(fabsf(t2), w2e, a1);  \
            float t3 = fmaf(w01, qbO, paO); a1 = fmaf(fabsf(t3), w2o, a1); }

        #pragma unroll 4
        for (int hp4 = 0; hp4 < 32; hp4++){
            uint4 pa4 = *reinterpret_cast<const uint4*>(P2 + si*128 + hp4*4);
            uint4 qa4 = *reinterpret_cast<const uint4*>(Q2 + sj*132 + hp4*4);
            uint4 qb4 = *reinterpret_cast<const uint4*>(Q2 + (sj+16)*132 + hp4*4);
            PROC(pa4.x, qa4.x, qb4.x, hp4*8+0)
            PROC(pa4.y, qa4.y, qb4.y, hp4*8+2)
            PROC(pa4.z, qa4.z, qb4.z, hp4*8+4)
            PROC(pa4.w, qa4.w, qb4.w, hp4*8+6)
        }
        #undef PROC

        float* ov = out_v + (size_t)b*1024;
        ov[si*32 + sj]      = fmaf(0.495f, a0, 0.505f*(SPi + w00*SQa));
        ov[si*32 + sj + 16] = fmaf(0.495f, a1, 0.505f*(SPi + w01*SQb));
    }
}

extern "C" void kernel_launch(void* const* d_in, const int* in_sizes, int n_in,
                              void* d_out, int out_size, void* d_ws, size_t ws_size,
                              hipStream_t stream) {
    const float* states = (const float*)d_in[0];
    const float* pol    = (const float*)d_in[1];
    const float* act    = (const float*)d_in[2];
    const float* Wkp    = (const float*)d_in[3];
    const float* Wqp    = (const float*)d_in[4];
    const float* Wvp    = (const float*)d_in[5];
    const float* Wk     = (const float*)d_in[6];
    const float* Wq     = (const float*)d_in[7];
    const float* We     = (const float*)d_in[8];
    const float* Wav    = (const float*)d_in[9];
    const float* W1     = (const float*)d_in[10];
    const float* W2     = (const float*)d_in[11];

    float* out    = (float*)d_out;
    float* out_v  = out;                 // [256,32,32,1]
    float* out_w1 = out + 256*1024;      // [256,32,32]
    float* out_w2 = out + 2*256*1024;    // [256,32,32]

    // workspace layout (floats)
    float* WABf = (float*)d_ws;                                  // [144][256] (rows 128..143 used)
    unsigned short* WABs = (unsigned short*)(WABf + 36864);      // 80 frags
    unsigned short* wsu  = (unsigned short*)(WABf + 57344);
    unsigned short* Wqps = wsu;             // 32 frags each
    unsigned short* Wkps = wsu + 16384;
    unsigned short* Wvqs = wsu + 32768;
    unsigned short* Wvks = wsu + 49152;
    unsigned long long* flags = (unsigned long long*)(WABf + 90112);  // 40 x 8B

    hipLaunchKernelGGL(k_all, dim3(NB), dim3(512), 0, stream,
                       states, pol, act, Wkp, Wqp, Wvp, Wk, Wq, We, Wav, W1, W2,
                       out_v, out_w1, out_w2,
                       WABf, WABs, Wqps, Wkps, Wvqs, Wvks, flags);
}

// Round 13
// 38.405 us; speedup vs baseline: 3.1480x; 1.0902x over previous
//
#include <hip/hip_runtime.h>
#include <math.h>

// Problem constants
#define NB 256   // batches
#define NN 32    // agents
#define DD 128   // state dim
#define NA 16    // action dim
#define HH 256   // hidden

using f32x4v  = __attribute__((ext_vector_type(4))) float;
using bf16x8  = __attribute__((ext_vector_type(8))) short;

static __device__ __forceinline__ float4 ld4(const float* p){ return *reinterpret_cast<const float4*>(p); }
static __device__ __forceinline__ void st4f(float* p, float4 v){ *reinterpret_cast<float4*>(p) = v; }
static __device__ __forceinline__ float elem(float4 v, int kk){
    return (kk==0)?v.x:(kk==1)?v.y:(kk==2)?v.z:v.w;
}

static __device__ __forceinline__ unsigned f2bf(float x){
    unsigned u = __float_as_uint(x);
    u += 0x7fffu + ((u >> 16) & 1u);   // round-to-nearest-even
    return u >> 16;
}
static __device__ __forceinline__ unsigned pack2(float a, float b){
    return f2bf(a) | (f2bf(b) << 16);
}

static __device__ __forceinline__ f32x4v mfma16(bf16x8 a, bf16x8 b, f32x4v c){
    return __builtin_amdgcn_mfma_f32_16x16x32_bf16(a, b, c, 0, 0, 0);
}

static __device__ __forceinline__ bf16x8 to_bf8(const float v[8]){
    union { bf16x8 v8; unsigned u[4]; } r;
    #pragma unroll
    for (int j = 0; j < 4; j++) r.u[j] = pack2(v[2*j], v[2*j+1]);
    return r.v8;
}

// write one B-fragment (16 bf16 bytes per lane) to the swizzled weight buffer
static __device__ __forceinline__ void store_frag(unsigned short* __restrict__ dst,
                                                  int frag, int l, const float v[8]){
    uint4 p;
    p.x = pack2(v[0], v[1]); p.y = pack2(v[2], v[3]);
    p.z = pack2(v[4], v[5]); p.w = pack2(v[6], v[7]);
    *reinterpret_cast<uint4*>(dst + (size_t)(frag*64 + l)*8) = p;
}

// =============================================================================
// k_pre (40 blocks x 512), MFMA-based:
//   0..15 : WAB col-tile (2-stage MFMA) -> WABs frags + WABf rows 128..143
//   16..23: Wqp/Wkp fragment swizzles (8 frags each)
//   24..31: Wvq = Wvp@Wq col-tile (MFMA) -> Wvqs frags
//   32..39: Wvk = Wvp@Wk col-tile (MFMA) -> Wvks frags
// Fragment layout (16x16x32 B-frag): frag (kt,nt): lane l holds
//   B[kt*32+(l>>4)*8+i][nt*16+(l&15)], i=0..7.
// =============================================================================
__global__ __launch_bounds__(512)
void k_pre(const float* __restrict__ We, const float* __restrict__ Wav,
           const float* __restrict__ W1,
           const float* __restrict__ Wqp, const float* __restrict__ Wkp,
           const float* __restrict__ Wvp, const float* __restrict__ Wq,
           const float* __restrict__ Wk,
           float* __restrict__ WABf, unsigned short* __restrict__ WABs,
           unsigned short* __restrict__ Wqps, unsigned short* __restrict__ Wkps,
           unsigned short* __restrict__ Wvqs, unsigned short* __restrict__ Wvks)
{
    __shared__ float SH[5120];
    const int t = threadIdx.x;
    const int bid = blockIdx.x;
    const int l   = t & 63;
    const int wvv = t >> 6;
    const int lg  = l >> 4;
    const int lc  = l & 15;

    if (bid < 16) {
        float* T2f  = SH;          // [128][20]
        float* WABt = SH + 2560;   // [160][16]
        const int ct = bid;
        // T2-stage: T2 = Wav @ W1[:,ct*16..)
        {
            const int arow = wvv*16 + lc;
            f32x4v acc = {0.f,0.f,0.f,0.f};
            #pragma unroll
            for (int kt = 0; kt < 4; kt++) {
                const float* ap = Wav + (size_t)arow*128 + kt*32 + lg*8;
                float4 a0 = ld4(ap), a1 = ld4(ap + 4);
                float av8[8] = {a0.x,a0.y,a0.z,a0.w,a1.x,a1.y,a1.z,a1.w};
                const float* bp = W1 + (size_t)(kt*32 + lg*8)*256 + ct*16 + lc;
                float bv8[8];
                #pragma unroll
                for (int i = 0; i < 8; i++) bv8[i] = bp[(size_t)i*256];
                acc = mfma16(to_bf8(av8), to_bf8(bv8), acc);
            }
            const int dr = wvv*16 + lg*4;
            #pragma unroll
            for (int r = 0; r < 4; r++) T2f[(dr+r)*20 + lc] = acc[r];
        }
        __syncthreads();
        // WAB-stage: We_pad @ T2 (M-tiles 0..9)
        #pragma unroll
        for (int pass = 0; pass < 2; pass++) {
            const int mt9 = (pass == 0) ? wvv : 8 + wvv;
            if (pass == 1 && wvv >= 2) continue;
            const int arow = mt9*16 + lc;
            f32x4v acc = {0.f,0.f,0.f,0.f};
            #pragma unroll
            for (int kt = 0; kt < 4; kt++) {
                float av8[8];
                if (arow < 144) {
                    const float* ap = We + (size_t)arow*128 + kt*32 + lg*8;
                    float4 a0 = ld4(ap), a1 = ld4(ap + 4);
                    av8[0]=a0.x; av8[1]=a0.y; av8[2]=a0.z; av8[3]=a0.w;
                    av8[4]=a1.x; av8[5]=a1.y; av8[6]=a1.z; av8[7]=a1.w;
                } else {
                    #pragma unroll
                    for (int i = 0; i < 8; i++) av8[i] = 0.f;
                }
                float bv8[8];
                #pragma unroll
                for (int i = 0; i < 8; i++) bv8[i] = T2f[(kt*32 + lg*8 + i)*20 + lc];
                acc = mfma16(to_bf8(av8), to_bf8(bv8), acc);
            }
            const int dr = mt9*16 + lg*4;
            #pragma unroll
            for (int r = 0; r < 4; r++) WABt[(dr+r)*16 + lc] = acc[r];
            if (mt9 == 8) {
                #pragma unroll
                for (int r = 0; r < 4; r++)
                    WABf[(size_t)(dr+r)*256 + ct*16 + lc] = acc[r];
            }
        }
        __syncthreads();
        if (t < 320) {
            int kt = t >> 6, ll = t & 63;
            float v[8];
            #pragma unroll
            for (int i = 0; i < 8; i++)
                v[i] = WABt[(kt*32 + (ll>>4)*8 + i)*16 + (ll&15)];
            store_frag(WABs, kt*16 + ct, ll, v);
        }
    } else if (bid < 24) {
        // Wqp/Wkp fragment swizzles: 8 frags/block over 64 total
        const int bb = bid - 16;
        const int fg = bb*8 + (t >> 6);
        const int sel = fg >> 5, frag = fg & 31;
        const int kt = frag >> 3, nt = frag & 7;
        const float* W = (sel==0) ? Wqp : Wkp;
        unsigned short* dst = (sel==0) ? Wqps : Wkps;
        float v[8];
        #pragma unroll
        for (int i = 0; i < 8; i++)
            v[i] = W[(kt*32 + (l>>4)*8 + i)*128 + nt*16 + (l&15)];
        store_frag(dst, frag, l, v);
    } else {
        // Wvq (24..31) / Wvk (32..39): col tile ct, M=128,N=16,K=128
        float* T2f = SH;    // [128][20]
        const int ct = (bid - 24) & 7;
        const float* Bsrc = (bid < 32) ? Wq : Wk;
        unsigned short* dst = (bid < 32) ? Wvqs : Wvks;
        {
            const int arow = wvv*16 + lc;
            f32x4v acc = {0.f,0.f,0.f,0.f};
            #pragma unroll
            for (int kt = 0; kt < 4; kt++) {
                const float* ap = Wvp + (size_t)arow*128 + kt*32 + lg*8;
                float4 a0 = ld4(ap), a1 = ld4(ap + 4);
                float av8[8] = {a0.x,a0.y,a0.z,a0.w,a1.x,a1.y,a1.z,a1.w};
                const float* bp = Bsrc + (size_t)(kt*32 + lg*8)*128 + ct*16 + lc;
                float bv8[8];
                #pragma unroll
                for (int i = 0; i < 8; i++) bv8[i] = bp[(size_t)i*128];
                acc = mfma16(to_bf8(av8), to_bf8(bv8), acc);
            }
            const int dr = wvv*16 + lg*4;
            #pragma unroll
            for (int r = 0; r < 4; r++) T2f[(dr+r)*20 + lc] = acc[r];
        }
        __syncthreads();
        if (t < 256) {
            int kt = t >> 6, ll = t & 63;
            float v[8];
            #pragma unroll
            for (int i = 0; i < 8; i++)
                v[i] = T2f[(kt*32 + (ll>>4)*8 + i)*20 + (ll&15)];
            store_frag(dst, kt*8 + ct, ll, v);
        }
    }
}

// scores+softmax, 512 threads: thread (i=t>>4, j=t&15) covers (i,j) and (i,j+16).
static __device__ __forceinline__ void scores_softmax512(const float* __restrict__ Qm,
                                                         const float* __restrict__ Km,
                                                         float scale,
                                                         float* __restrict__ w_lds,
                                                         float* __restrict__ w_out,
                                                         int i, int j)
{
    float s0 = 0.f, s1 = 0.f;
    #pragma unroll 4
    for (int k=0;k<128;k+=4){
        float4 qv = ld4(Qm + i*132 + k);
        float4 k0 = ld4(Km + j*132 + k);
        float4 k1 = ld4(Km + (j+16)*132 + k);
        s0 += qv.x*k0.x + qv.y*k0.y + qv.z*k0.z + qv.w*k0.w;
        s1 += qv.x*k1.x + qv.y*k1.y + qv.z*k1.z + qv.w*k1.w;
    }
    s0 *= scale; s1 *= scale;
    float m = fmaxf(s0, s1);
    #pragma unroll
    for (int d=1; d<16; d<<=1) m = fmaxf(m, __shfl_xor(m, d));
    float e0 = expf(s0 - m), e1 = expf(s1 - m);
    float sum = e0 + e1;
    #pragma unroll
    for (int d=1; d<16; d<<=1) sum += __shfl_xor(sum, d);
    float inv = 1.f / sum;
    e0 *= inv; e1 *= inv;
    w_lds[i*36 + j]      = e0;
    w_lds[i*36 + j + 16] = e1;
    w_out[i*32 + j]      = e0;
    w_out[i*32 + j + 16] = e1;
}

// =============================================================================
// k_main: one block per batch, 512 threads. Shortened chain:
//   stage -> P1 (q1,k1,svq,svk: 4-stream MFMA; svq/svk in regs) -> sm1 ->
//   svq/svk store -> P3' (q2,k2 = w1@{svq,svk}, VALU K=32) -> sm2 ->
//   P7 (A1 MFMA) -> P8 (P=w2@A1 + SP) -> P9 (Q + SQ) -> P10 epilogue.
// =============================================================================
__global__ __launch_bounds__(512)
void k_main(const float* __restrict__ states, const float* __restrict__ pol,
            const float* __restrict__ act,
            const unsigned short* __restrict__ Wqps, const unsigned short* __restrict__ Wkps,
            const unsigned short* __restrict__ Wvqs, const unsigned short* __restrict__ Wvks,
            const unsigned short* __restrict__ WABs, const float* __restrict__ WABf,
            const float* __restrict__ W2,
            float* __restrict__ out_v, float* __restrict__ out_w1,
            float* __restrict__ out_w2)
{
    const int b = blockIdx.x;
    const int t = threadIdx.x;
    const float scale = 0.08838834764831845f;  // 1/sqrt(128)

    __shared__ float SH[15360];   // 60 KB
    float* B1   = SH;                                     // [32][132]
    float* B2   = SH + 4224;                              // [32][132]
    float* Wb1f = SH + 8448;                              // [32][36]
    float* Wb2f = SH + 9600;                              // [32][36]
    float* APd  = SH + 10752;                             // [32][16]
    unsigned short* Xoa = (unsigned short*)(SH + 11264);  // [32][168] bf16
    float*    A1 = SH;                                    // [32][260] over B1+B2
    unsigned* P2 = (unsigned*)(SH + 11264);               // [32][128] over dead Xoa
    unsigned* Q2 = (unsigned*)SH;                         // [32][132] over dead A1
    float* SPQ = Wb1f;                                    // SP/SQ over dead Wb1f

    const float* stg  = states + (size_t)b*(NN*DD);
    const float* actg = act + (size_t)b*(NN*NA);
    const float* polg = pol + (size_t)b*(NN*NA);

    const int l   = t & 63;
    const int wvv = t >> 6;
    const int lg  = l >> 4;
    const int lc  = l & 15;

    // ---- stage Xoa = bf16([st | act | 0]), APd = pol-act ----
    {
        int r = t >> 4, kb = t & 15;
        #pragma unroll
        for (int uu = 0; uu < 10; uu++){
            int k = kb + 16*uu;
            float v = (k < 128) ? stg[r*128 + k]
                    : (k < 144) ? actg[r*16 + (k-128)] : 0.f;
            Xoa[r*168 + k] = (unsigned short)f2bf(v);
        }
        if (t < 128) {
            int rr = t>>2, cc = (t&3)*4;
            float4 p = ld4(polg + rr*16 + cc), a = ld4(actg + rr*16 + cc);
            st4f(APd + rr*16 + cc, make_float4(p.x-a.x, p.y-a.y, p.z-a.z, p.w-a.w));
        }
    }
    __syncthreads();

    // geometry
    const int mt   = wvv & 1;
    const int ntb  = (wvv >> 1) * 2;
    const int nb7  = (wvv >> 1) * 4;
    const int arow = mt*16 + lc;
    const int drow = mt*16 + (lg << 2);
    const int dcol = lc;
    const int c  = t & 127;
    const int g  = t >> 7;
    const int cp = (t & 127)*2;
    const int si = t >> 4;
    const int sj = t & 15;
    const int wp = wvv & 1;

    // ---- P1 (MFMA x4): q1->B1, k1->B2, svq/svk -> regs ----
    f32x4v asq0={0.f,0.f,0.f,0.f}, asq1={0.f,0.f,0.f,0.f};
    f32x4v ask0={0.f,0.f,0.f,0.f}, ask1={0.f,0.f,0.f,0.f};
    {
        f32x4v aq0={0.f,0.f,0.f,0.f}, aq1={0.f,0.f,0.f,0.f};
        f32x4v ak0={0.f,0.f,0.f,0.f}, ak1={0.f,0.f,0.f,0.f};
        const unsigned short* ab = Xoa + arow*168 + lg*8;
        #pragma unroll
        for (int kt = 0; kt < 4; kt++){
            bf16x8 a = *reinterpret_cast<const bf16x8*>(ab + kt*32);
            bf16x8 bq0 = *reinterpret_cast<const bf16x8*>(Wqps + (size_t)((kt*8+ntb  )*64 + l)*8);
            bf16x8 bq1 = *reinterpret_cast<const bf16x8*>(Wqps + (size_t)((kt*8+ntb+1)*64 + l)*8);
            bf16x8 bk0 = *reinterpret_cast<const bf16x8*>(Wkps + (size_t)((kt*8+ntb  )*64 + l)*8);
            bf16x8 bk1 = *reinterpret_cast<const bf16x8*>(Wkps + (size_t)((kt*8+ntb+1)*64 + l)*8);
            bf16x8 bv0 = *reinterpret_cast<const bf16x8*>(Wvqs + (size_t)((kt*8+ntb  )*64 + l)*8);
            bf16x8 bv1 = *reinterpret_cast<const bf16x8*>(Wvqs + (size_t)((kt*8+ntb+1)*64 + l)*8);
            bf16x8 bw0 = *reinterpret_cast<const bf16x8*>(Wvks + (size_t)((kt*8+ntb  )*64 + l)*8);
            bf16x8 bw1 = *reinterpret_cast<const bf16x8*>(Wvks + (size_t)((kt*8+ntb+1)*64 + l)*8);
            aq0 = mfma16(a, bq0, aq0); aq1 = mfma16(a, bq1, aq1);
            ak0 = mfma16(a, bk0, ak0); ak1 = mfma16(a, bk1, ak1);
            asq0 = mfma16(a, bv0, asq0); asq1 = mfma16(a, bv1, asq1);
            ask0 = mfma16(a, bw0, ask0); ask1 = mfma16(a, bw1, ask1);
        }
        #pragma unroll
        for (int r = 0; r < 4; r++){
            B1[(drow+r)*132 + ntb*16     + dcol] = aq0[r];
            B1[(drow+r)*132 + (ntb+1)*16 + dcol] = aq1[r];
            B2[(drow+r)*132 + ntb*16     + dcol] = ak0[r];
            B2[(drow+r)*132 + (ntb+1)*16 + dcol] = ak1[r];
        }
    }
    __syncthreads();

    // ---- sm1: w1 = softmax(q1@k1^T * scale) ----
    scores_softmax512(B1, B2, scale, Wb1f, out_w1 + (size_t)b*1024, si, sj);
    __syncthreads();

    // ---- store svq/svk over dead q1/k1 ----
    #pragma unroll
    for (int r = 0; r < 4; r++){
        B1[(drow+r)*132 + ntb*16     + dcol] = asq0[r];
        B1[(drow+r)*132 + (ntb+1)*16 + dcol] = asq1[r];
        B2[(drow+r)*132 + ntb*16     + dcol] = ask0[r];
        B2[(drow+r)*132 + (ntb+1)*16 + dcol] = ask1[r];
    }
    __syncthreads();

    // ---- P3': q2 = w1@SVQ, k2 = w1@SVK (VALU K=32) -> regs -> B1,B2 ----
    {
        float q2a[8], k2a[8];
        #pragma unroll
        for (int u=0;u<8;u++){ q2a[u]=0.f; k2a[u]=0.f; }
        #pragma unroll
        for (int k0=0;k0<32;k0+=4){
            float4 xv[8];
            #pragma unroll
            for (int u=0;u<8;u++) xv[u] = ld4(Wb1f + (g*8+u)*36 + k0);
            #pragma unroll
            for (int kk=0;kk<4;kk++){
                float vq = B1[(k0+kk)*132 + c];
                float vk = B2[(k0+kk)*132 + c];
                #pragma unroll
                for (int u=0;u<8;u++){
                    float x = elem(xv[u],kk);
                    q2a[u] = fmaf(x, vq, q2a[u]);
                    k2a[u] = fmaf(x, vk, k2a[u]);
                }
            }
        }
        __syncthreads();   // SVQ/SVK reads done
        #pragma unroll
        for (int u=0;u<8;u++){
            B1[(g*8+u)*132 + c] = q2a[u];
            B2[(g*8+u)*132 + c] = k2a[u];
        }
    }
    __syncthreads();

    // ---- sm2: w2 = softmax(q2@k2^T * scale) ----
    scores_softmax512(B1, B2, scale, Wb2f, out_w2 + (size_t)b*1024, si, sj);
    __syncthreads();

    // ---- P7 (MFMA): A1 = [st|act|0]@WAB (K=160,N=256) -> A1 (over B1/B2) ----
    {
        f32x4v ac[4];
        #pragma unroll
        for (int n=0;n<4;n++) ac[n] = f32x4v{0.f,0.f,0.f,0.f};
        const unsigned short* ab = Xoa + arow*168 + lg*8;
        #pragma unroll
        for (int kt = 0; kt < 5; kt++){
            bf16x8 a = *reinterpret_cast<const bf16x8*>(ab + kt*32);
            #pragma unroll
            for (int n = 0; n < 4; n++){
                bf16x8 bb = *reinterpret_cast<const bf16x8*>(WABs + (size_t)((kt*16 + nb7 + n)*64 + l)*8);
                ac[n] = mfma16(a, bb, ac[n]);
            }
        }
        #pragma unroll
        for (int n = 0; n < 4; n++){
            #pragma unroll
            for (int r = 0; r < 4; r++)
                A1[(drow+r)*260 + (nb7+n)*16 + dcol] = ac[n][r];
        }
    }
    __syncthreads();

    // ---- P8 (VALU): P = w2@A1 (K=32) -> bf16 P2 (over dead Xoa) + SP ----
    {
        float ap0[8], ap1[8];
        #pragma unroll
        for (int u=0;u<8;u++){ ap0[u]=0.f; ap1[u]=0.f; }
        #pragma unroll
        for (int k0=0;k0<32;k0+=4){
            float4 xv[8];
            #pragma unroll
            for (int u=0;u<8;u++) xv[u] = ld4(Wb2f + (g*8+u)*36 + k0);
            #pragma unroll
            for (int kk=0;kk<4;kk++){
                float2 w = *reinterpret_cast<const float2*>(A1 + (k0+kk)*260 + cp);
                #pragma unroll
                for (int u=0;u<8;u++){
                    float x = elem(xv[u],kk);
                    ap0[u] = fmaf(x, w.x, ap0[u]);
                    ap1[u] = fmaf(x, w.y, ap1[u]);
                }
            }
        }
        #pragma unroll
        for (int u=0;u<8;u++)
            P2[(g*8+u)*128 + (cp>>1)] = pack2(ap0[u], ap1[u]);
        float2 w2v = *reinterpret_cast<const float2*>(W2 + cp);
        float sp[8];
        #pragma unroll
        for (int u=0;u<8;u++) sp[u] = ap0[u]*w2v.x + ap1[u]*w2v.y;
        #pragma unroll
        for (int d=1; d<64; d<<=1){
            #pragma unroll
            for (int u=0;u<8;u++) sp[u] += __shfl_xor(sp[u], d);
        }
        if (l == 0){
            #pragma unroll
            for (int u=0;u<8;u++) SPQ[(g*8+u)*2 + wp] = sp[u];
        }
    }
    __syncthreads();

    // ---- P9 (VALU): Q = (pol-act)@WB -> bf16 Q2 (over dead A1) + SQ ----
    {
        float aq0[8], aq1[8];
        #pragma unroll
        for (int u=0;u<8;u++){ aq0[u]=0.f; aq1[u]=0.f; }
        const float* wB = WABf + 128*256;
        #pragma unroll
        for (int k0=0;k0<16;k0+=4){
            float4 xv[8];
            #pragma unroll
            for (int u=0;u<8;u++) xv[u] = ld4(APd + (g*8+u)*16 + k0);
            #pragma unroll
            for (int kk=0;kk<4;kk++){
                float2 w = *reinterpret_cast<const float2*>(wB + (k0+kk)*256 + cp);
                #pragma unroll
                for (int u=0;u<8;u++){
                    float x = elem(xv[u],kk);
                    aq0[u] = fmaf(x, w.x, aq0[u]);
                    aq1[u] = fmaf(x, w.y, aq1[u]);
                }
            }
        }
        #pragma unroll
        for (int u=0;u<8;u++)
            Q2[(g*8+u)*132 + (cp>>1)] = pack2(aq0[u], aq1[u]);
        float2 w2v = *reinterpret_cast<const float2*>(W2 + cp);
        float sq[8];
        #pragma unroll
        for (int u=0;u<8;u++) sq[u] = aq0[u]*w2v.x + aq1[u]*w2v.y;
        #pragma unroll
        for (int d=1; d<64; d<<=1){
            #pragma unroll
            for (int u=0;u<8;u++) sq[u] += __shfl_xor(sq[u], d);
        }
        if (l == 0){
            #pragma unroll
            for (int u=0;u<8;u++) SPQ[64 + (g*8+u)*2 + wp] = sq[u];
        }
    }
    __syncthreads();

    // ---- P10: value[i,j] = 0.505*(SP[i]+w*SQ[j]) + 0.495*sum_h W2[h]*|..| ----
    {
        float w00 = Wb2f[si*36 + sj], w01 = Wb2f[si*36 + sj + 16];
        float SPi = SPQ[si*2] + SPQ[si*2+1];
        float SQa = SPQ[64 + sj*2] + SPQ[64 + sj*2+1];
        float SQb = SPQ[64 + (sj+16)*2] + SPQ[64 + (sj+16)*2+1];
        float a0 = 0.f, a1 = 0.f;

        #define PROC(PA,QA,QB,H2) {                                         \
            float w2e = W2[(H2)], w2o = W2[(H2)+1];                         \
            float paE = __uint_as_float((PA)<<16), paO = __uint_as_float((PA) & 0xffff0000u); \
            float qaE = __uint_as_float((QA)<<16), qaO = __uint_as_float((QA) & 0xffff0000u); \
            float qbE = __uint_as_float((QB)<<16), qbO = __uint_as_float((QB) & 0xffff0000u); \
            float t0 = fmaf(w00, qaE, paE); a0 = fmaf(fabsf(t0), w2e, a0);  \
            float t1 = fmaf(w00, qaO, paO); a0 = fmaf(fabsf(t1), w2o, a0);  \
            float t2 = fmaf(w01, qbE, paE); a1 = fmaf(fabsf(t2), w2e, a1);  \
            float t3 = fmaf(w01, qbO, paO); a1 = fmaf(fabsf(t3), w2o, a1); }

        #pragma unroll 4
        for (int hp4 = 0; hp4 < 32; hp4++){
            uint4 pa4 = *reinterpret_cast<const uint4*>(P2 + si*128 + hp4*4);
            uint4 qa4 = *reinterpret_cast<const uint4*>(Q2 + sj*132 + hp4*4);
            uint4 qb4 = *reinterpret_cast<const uint4*>(Q2 + (sj+16)*132 + hp4*4);
            PROC(pa4.x, qa4.x, qb4.x, hp4*8+0)
            PROC(pa4.y, qa4.y, qb4.y, hp4*8+2)
            PROC(pa4.z, qa4.z, qb4.z, hp4*8+4)
            PROC(pa4.w, qa4.w, qb4.w, hp4*8+6)
        }
        #undef PROC

        float* ov = out_v + (size_t)b*1024;
        ov[si*32 + sj]      = fmaf(0.495f, a0, 0.505f*(SPi + w00*SQa));
        ov[si*32 + sj + 16] = fmaf(0.495f, a1, 0.505f*(SPi + w01*SQb));
    }
}

extern "C" void kernel_launch(void* const* d_in, const int* in_sizes, int n_in,
                              void* d_out, int out_size, void* d_ws, size_t ws_size,
                              hipStream_t stream) {
    const float* states = (const float*)d_in[0];
    const float* pol    = (const float*)d_in[1];
    const float* act    = (const float*)d_in[2];
    const float* Wkp    = (const float*)d_in[3];
    const float* Wqp    = (const float*)d_in[4];
    const float* Wvp    = (const float*)d_in[5];
    const float* Wk     = (const float*)d_in[6];
    const float* Wq     = (const float*)d_in[7];
    const float* We     = (const float*)d_in[8];
    const float* Wav    = (const float*)d_in[9];
    const float* W1     = (const float*)d_in[10];
    const float* W2     = (const float*)d_in[11];

    float* out    = (float*)d_out;
    float* out_v  = out;                 // [256,32,32,1]
    float* out_w1 = out + 256*1024;      // [256,32,32]
    float* out_w2 = out + 2*256*1024;    // [256,32,32]

    // workspace layout (floats)
    float* WABf = (float*)d_ws;                                  // [144][256] (rows 128..143 used)
    unsigned short* WABs = (unsigned short*)(WABf + 36864);      // 80 frags
    unsigned short* wsu  = (unsigned short*)(WABf + 57344);
    unsigned short* Wqps = wsu;             // 32 frags each
    unsigned short* Wkps = wsu + 16384;
    unsigned short* Wvqs = wsu + 32768;
    unsigned short* Wvks = wsu + 49152;

    hipLaunchKernelGGL(k_pre, dim3(40), dim3(512), 0, stream,
                       We, Wav, W1, Wqp, Wkp, Wvp, Wq, Wk,
                       WABf, WABs, Wqps, Wkps, Wvqs, Wvks);
    hipLaunchKernelGGL(k_main, dim3(NB), dim3(512), 0, stream,
                       states, pol, act,
                       Wqps, Wkps, Wvqs, Wvks, WABs, WABf, W2,
                       out_v, out_w1, out_w2);
}

// Round 14
// 36.494 us; speedup vs baseline: 3.3128x; 1.0524x over previous
//
#include <hip/hip_runtime.h>
#include <math.h>

// Problem constants
#define NB 256   // batches
#define NN 32    // agents
#define DD 128   // state dim
#define NA 16    // action dim
#define HH 256   // hidden

using f32x4v  = __attribute__((ext_vector_type(4))) float;
using bf16x8  = __attribute__((ext_vector_type(8))) short;

static __device__ __forceinline__ float4 ld4(const float* p){ return *reinterpret_cast<const float4*>(p); }
static __device__ __forceinline__ void st4f(float* p, float4 v){ *reinterpret_cast<float4*>(p) = v; }
static __device__ __forceinline__ float elem(float4 v, int kk){
    return (kk==0)?v.x:(kk==1)?v.y:(kk==2)?v.z:v.w;
}

static __device__ __forceinline__ unsigned f2bf(float x){
    unsigned u = __float_as_uint(x);
    u += 0x7fffu + ((u >> 16) & 1u);   // round-to-nearest-even
    return u >> 16;
}
static __device__ __forceinline__ unsigned pack2(float a, float b){
    return f2bf(a) | (f2bf(b) << 16);
}

static __device__ __forceinline__ f32x4v mfma16(bf16x8 a, bf16x8 b, f32x4v c){
    return __builtin_amdgcn_mfma_f32_16x16x32_bf16(a, b, c, 0, 0, 0);
}

static __device__ __forceinline__ bf16x8 to_bf8(const float v[8]){
    union { bf16x8 v8; unsigned u[4]; } r;
    #pragma unroll
    for (int j = 0; j < 4; j++) r.u[j] = pack2(v[2*j], v[2*j+1]);
    return r.v8;
}

// write one B-fragment (16 bf16 bytes per lane) to the swizzled weight buffer
static __device__ __forceinline__ void store_frag(unsigned short* __restrict__ dst,
                                                  int frag, int l, const float v[8]){
    uint4 p;
    p.x = pack2(v[0], v[1]); p.y = pack2(v[2], v[3]);
    p.z = pack2(v[4], v[5]); p.w = pack2(v[6], v[7]);
    *reinterpret_cast<uint4*>(dst + (size_t)(frag*64 + l)*8) = p;
}

// =============================================================================
// k_pre (40 blocks x 512), MFMA-based (identical to R13):
//   0..15 : WAB col-tile (2-stage MFMA) -> WABs frags + WABf rows 128..143
//   16..23: Wqp/Wkp fragment swizzles
//   24..31: Wvq = Wvp@Wq col-tile -> Wvqs frags
//   32..39: Wvk = Wvp@Wk col-tile -> Wvks frags
// =============================================================================
__global__ __launch_bounds__(512)
void k_pre(const float* __restrict__ We, const float* __restrict__ Wav,
           const float* __restrict__ W1,
           const float* __restrict__ Wqp, const float* __restrict__ Wkp,
           const float* __restrict__ Wvp, const float* __restrict__ Wq,
           const float* __restrict__ Wk,
           float* __restrict__ WABf, unsigned short* __restrict__ WABs,
           unsigned short* __restrict__ Wqps, unsigned short* __restrict__ Wkps,
           unsigned short* __restrict__ Wvqs, unsigned short* __restrict__ Wvks)
{
    __shared__ float SH[5120];
    const int t = threadIdx.x;
    const int bid = blockIdx.x;
    const int l   = t & 63;
    const int wvv = t >> 6;
    const int lg  = l >> 4;
    const int lc  = l & 15;

    if (bid < 16) {
        float* T2f  = SH;          // [128][20]
        float* WABt = SH + 2560;   // [160][16]
        const int ct = bid;
        {
            const int arow = wvv*16 + lc;
            f32x4v acc = {0.f,0.f,0.f,0.f};
            #pragma unroll
            for (int kt = 0; kt < 4; kt++) {
                const float* ap = Wav + (size_t)arow*128 + kt*32 + lg*8;
                float4 a0 = ld4(ap), a1 = ld4(ap + 4);
                float av8[8] = {a0.x,a0.y,a0.z,a0.w,a1.x,a1.y,a1.z,a1.w};
                const float* bp = W1 + (size_t)(kt*32 + lg*8)*256 + ct*16 + lc;
                float bv8[8];
                #pragma unroll
                for (int i = 0; i < 8; i++) bv8[i] = bp[(size_t)i*256];
                acc = mfma16(to_bf8(av8), to_bf8(bv8), acc);
            }
            const int dr = wvv*16 + lg*4;
            #pragma unroll
            for (int r = 0; r < 4; r++) T2f[(dr+r)*20 + lc] = acc[r];
        }
        __syncthreads();
        #pragma unroll
        for (int pass = 0; pass < 2; pass++) {
            const int mt9 = (pass == 0) ? wvv : 8 + wvv;
            if (pass == 1 && wvv >= 2) continue;
            const int arow = mt9*16 + lc;
            f32x4v acc = {0.f,0.f,0.f,0.f};
            #pragma unroll
            for (int kt = 0; kt < 4; kt++) {
                float av8[8];
                if (arow < 144) {
                    const float* ap = We + (size_t)arow*128 + kt*32 + lg*8;
                    float4 a0 = ld4(ap), a1 = ld4(ap + 4);
                    av8[0]=a0.x; av8[1]=a0.y; av8[2]=a0.z; av8[3]=a0.w;
                    av8[4]=a1.x; av8[5]=a1.y; av8[6]=a1.z; av8[7]=a1.w;
                } else {
                    #pragma unroll
                    for (int i = 0; i < 8; i++) av8[i] = 0.f;
                }
                float bv8[8];
                #pragma unroll
                for (int i = 0; i < 8; i++) bv8[i] = T2f[(kt*32 + lg*8 + i)*20 + lc];
                acc = mfma16(to_bf8(av8), to_bf8(bv8), acc);
            }
            const int dr = mt9*16 + lg*4;
            #pragma unroll
            for (int r = 0; r < 4; r++) WABt[(dr+r)*16 + lc] = acc[r];
            if (mt9 == 8) {
                #pragma unroll
                for (int r = 0; r < 4; r++)
                    WABf[(size_t)(dr+r)*256 + ct*16 + lc] = acc[r];
            }
        }
        __syncthreads();
        if (t < 320) {
            int kt = t >> 6, ll = t & 63;
            float v[8];
            #pragma unroll
            for (int i = 0; i < 8; i++)
                v[i] = WABt[(kt*32 + (ll>>4)*8 + i)*16 + (ll&15)];
            store_frag(WABs, kt*16 + ct, ll, v);
        }
    } else if (bid < 24) {
        const int bb = bid - 16;
        const int fg = bb*8 + (t >> 6);
        const int sel = fg >> 5, frag = fg & 31;
        const int kt = frag >> 3, nt = frag & 7;
        const float* W = (sel==0) ? Wqp : Wkp;
        unsigned short* dst = (sel==0) ? Wqps : Wkps;
        float v[8];
        #pragma unroll
        for (int i = 0; i < 8; i++)
            v[i] = W[(kt*32 + (l>>4)*8 + i)*128 + nt*16 + (l&15)];
        store_frag(dst, frag, l, v);
    } else {
        float* T2f = SH;    // [128][20]
        const int ct = (bid - 24) & 7;
        const float* Bsrc = (bid < 32) ? Wq : Wk;
        unsigned short* dst = (bid < 32) ? Wvqs : Wvks;
        {
            const int arow = wvv*16 + lc;
            f32x4v acc = {0.f,0.f,0.f,0.f};
            #pragma unroll
            for (int kt = 0; kt < 4; kt++) {
                const float* ap = Wvp + (size_t)arow*128 + kt*32 + lg*8;
                float4 a0 = ld4(ap), a1 = ld4(ap + 4);
                float av8[8] = {a0.x,a0.y,a0.z,a0.w,a1.x,a1.y,a1.z,a1.w};
                const float* bp = Bsrc + (size_t)(kt*32 + lg*8)*128 + ct*16 + lc;
                float bv8[8];
                #pragma unroll
                for (int i = 0; i < 8; i++) bv8[i] = bp[(size_t)i*128];
                acc = mfma16(to_bf8(av8), to_bf8(bv8), acc);
            }
            const int dr = wvv*16 + lg*4;
            #pragma unroll
            for (int r = 0; r < 4; r++) T2f[(dr+r)*20 + lc] = acc[r];
        }
        __syncthreads();
        if (t < 256) {
            int kt = t >> 6, ll = t & 63;
            float v[8];
            #pragma unroll
            for (int i = 0; i < 8; i++)
                v[i] = T2f[(kt*32 + (ll>>4)*8 + i)*20 + (ll&15)];
            store_frag(dst, kt*8 + ct, ll, v);
        }
    }
}

// scores+softmax, 1024 threads: thread (i=t>>5, j=t&31) covers one (i,j).
// i-row occupies one 32-lane half-wave; reduce with shfl_xor d<32.
static __device__ __forceinline__ void scores_softmax1024(const float* __restrict__ Qm,
                                                          const float* __restrict__ Km,
                                                          float scale,
                                                          float* __restrict__ w_lds,
                                                          float* __restrict__ w_out,
                                                          int i, int j)
{
    float s0 = 0.f;
    #pragma unroll 4
    for (int k=0;k<128;k+=4){
        float4 qv = ld4(Qm + i*132 + k);
        float4 k0 = ld4(Km + j*132 + k);
        s0 += qv.x*k0.x + qv.y*k0.y + qv.z*k0.z + qv.w*k0.w;
    }
    s0 *= scale;
    float m = s0;
    #pragma unroll
    for (int d=1; d<32; d<<=1) m = fmaxf(m, __shfl_xor(m, d));
    float e0 = expf(s0 - m);
    float sum = e0;
    #pragma unroll
    for (int d=1; d<32; d<<=1) sum += __shfl_xor(sum, d);
    float w = e0 / sum;
    w_lds[i*36 + j] = w;
    w_out[i*32 + j] = w;
}

// =============================================================================
// k_main: one block per batch, 1024 threads (16 waves/CU).
//   stage -> P1 (q1,k1,svq,svk 4-stream MFMA; svq/svk in regs) -> sm1 ->
//   svq/svk store -> P3' (q2,k2 = w1@{svq,svk}) -> sm2 -> P7 (A1 MFMA) ->
//   P8 (P + SP) -> P9 (Q + SQ) -> P10 epilogue.
// =============================================================================
__global__ __launch_bounds__(1024)
void k_main(const float* __restrict__ states, const float* __restrict__ pol,
            const float* __restrict__ act,
            const unsigned short* __restrict__ Wqps, const unsigned short* __restrict__ Wkps,
            const unsigned short* __restrict__ Wvqs, const unsigned short* __restrict__ Wvks,
            const unsigned short* __restrict__ WABs, const float* __restrict__ WABf,
            const float* __restrict__ W2,
            float* __restrict__ out_v, float* __restrict__ out_w1,
            float* __restrict__ out_w2)
{
    const int b = blockIdx.x;
    const int t = threadIdx.x;
    const float scale = 0.08838834764831845f;  // 1/sqrt(128)

    __shared__ float SH[15360];   // 60 KB
    float* B1   = SH;                                     // [32][132]
    float* B2   = SH + 4224;                              // [32][132]
    float* Wb1f = SH + 8448;                              // [32][36]
    float* Wb2f = SH + 9600;                              // [32][36]
    float* APd  = SH + 10752;                             // [32][16]
    unsigned short* Xoa = (unsigned short*)(SH + 11264);  // [32][168] bf16
    float*    A1 = SH;                                    // [32][260] over B1+B2
    unsigned* P2 = (unsigned*)(SH + 11264);               // [32][128] over dead Xoa
    unsigned* Q2 = (unsigned*)SH;                         // [32][132] over dead A1
    float* SPQ = Wb1f;                                    // SP/SQ over dead Wb1f

    const float* stg  = states + (size_t)b*(NN*DD);
    const float* actg = act + (size_t)b*(NN*NA);
    const float* polg = pol + (size_t)b*(NN*NA);

    const int l   = t & 63;
    const int wvv = t >> 6;   // 0..15
    const int lg  = l >> 4;
    const int lc  = l & 15;

    // ---- stage Xoa = bf16([st | act | 0]), APd = pol-act ----
    {
        int r = t >> 5, kb = t & 31;
        #pragma unroll
        for (int uu = 0; uu < 5; uu++){
            int k = kb + 32*uu;
            float v = (k < 128) ? stg[r*128 + k]
                    : (k < 144) ? actg[r*16 + (k-128)] : 0.f;
            Xoa[r*168 + k] = (unsigned short)f2bf(v);
        }
        if (t < 128) {
            int rr = t>>2, cc = (t&3)*4;
            float4 p = ld4(polg + rr*16 + cc), a = ld4(actg + rr*16 + cc);
            st4f(APd + rr*16 + cc, make_float4(p.x-a.x, p.y-a.y, p.z-a.z, p.w-a.w));
        }
    }
    __syncthreads();

    // geometry (16 waves)
    const int mt   = wvv & 1;             // M-tile
    const int ntb  = wvv >> 1;            // N-tile (128-col GEMMs): 0..7
    const int nb7  = (wvv >> 1) * 2;      // N-tile base (256-col GEMM): 2 tiles
    const int arow = mt*16 + lc;
    const int drow = mt*16 + (lg << 2);
    const int dcol = lc;
    const int c  = t & 127;
    const int g  = t >> 7;                // 0..7 -> rows g*4..g*4+3
    const int cp = (t & 127)*2;
    const int si = t >> 5;                // 0..31
    const int sj = t & 31;                // 0..31
    const int wp = wvv & 1;

    // ---- P1 (MFMA x4): q1->B1, k1->B2, svq/svk -> regs ----
    f32x4v asq0={0.f,0.f,0.f,0.f};
    f32x4v ask0={0.f,0.f,0.f,0.f};
    {
        f32x4v aq0={0.f,0.f,0.f,0.f};
        f32x4v ak0={0.f,0.f,0.f,0.f};
        const unsigned short* ab = Xoa + arow*168 + lg*8;
        #pragma unroll
        for (int kt = 0; kt < 4; kt++){
            bf16x8 a = *reinterpret_cast<const bf16x8*>(ab + kt*32);
            bf16x8 bq0 = *reinterpret_cast<const bf16x8*>(Wqps + (size_t)((kt*8+ntb)*64 + l)*8);
            bf16x8 bk0 = *reinterpret_cast<const bf16x8*>(Wkps + (size_t)((kt*8+ntb)*64 + l)*8);
            bf16x8 bv0 = *reinterpret_cast<const bf16x8*>(Wvqs + (size_t)((kt*8+ntb)*64 + l)*8);
            bf16x8 bw0 = *reinterpret_cast<const bf16x8*>(Wvks + (size_t)((kt*8+ntb)*64 + l)*8);
            aq0 = mfma16(a, bq0, aq0);
            ak0 = mfma16(a, bk0, ak0);
            asq0 = mfma16(a, bv0, asq0);
            ask0 = mfma16(a, bw0, ask0);
        }
        #pragma unroll
        for (int r = 0; r < 4; r++){
            B1[(drow+r)*132 + ntb*16 + dcol] = aq0[r];
            B2[(drow+r)*132 + ntb*16 + dcol] = ak0[r];
        }
    }
    __syncthreads();

    // ---- sm1: w1 = softmax(q1@k1^T * scale) ----
    scores_softmax1024(B1, B2, scale, Wb1f, out_w1 + (size_t)b*1024, si, sj);
    __syncthreads();

    // ---- store svq/svk over dead q1/k1 ----
    #pragma unroll
    for (int r = 0; r < 4; r++){
        B1[(drow+r)*132 + ntb*16 + dcol] = asq0[r];
        B2[(drow+r)*132 + ntb*16 + dcol] = ask0[r];
    }
    __syncthreads();

    // ---- P3': q2 = w1@SVQ, k2 = w1@SVK (VALU K=32) -> regs -> B1,B2 ----
    {
        float q2a[4], k2a[4];
        #pragma unroll
        for (int u=0;u<4;u++){ q2a[u]=0.f; k2a[u]=0.f; }
        #pragma unroll
        for (int k0=0;k0<32;k0+=4){
            float4 xv[4];
            #pragma unroll
            for (int u=0;u<4;u++) xv[u] = ld4(Wb1f + (g*4+u)*36 + k0);
            #pragma unroll
            for (int kk=0;kk<4;kk++){
                float vq = B1[(k0+kk)*132 + c];
                float vk = B2[(k0+kk)*132 + c];
                #pragma unroll
                for (int u=0;u<4;u++){
                    float x = elem(xv[u],kk);
                    q2a[u] = fmaf(x, vq, q2a[u]);
                    k2a[u] = fmaf(x, vk, k2a[u]);
                }
            }
        }
        __syncthreads();   // SVQ/SVK reads done
        #pragma unroll
        for (int u=0;u<4;u++){
            B1[(g*4+u)*132 + c] = q2a[u];
            B2[(g*4+u)*132 + c] = k2a[u];
        }
    }
    __syncthreads();

    // ---- sm2: w2 = softmax(q2@k2^T * scale) ----
    scores_softmax1024(B1, B2, scale, Wb2f, out_w2 + (size_t)b*1024, si, sj);
    __syncthreads();

    // ---- P7 (MFMA): A1 = [st|act|0]@WAB (K=160,N=256) -> A1 (over B1/B2) ----
    {
        f32x4v ac[2];
        #pragma unroll
        for (int n=0;n<2;n++) ac[n] = f32x4v{0.f,0.f,0.f,0.f};
        const unsigned short* ab = Xoa + arow*168 + lg*8;
        #pragma unroll
        for (int kt = 0; kt < 5; kt++){
            bf16x8 a = *reinterpret_cast<const bf16x8*>(ab + kt*32);
            #pragma unroll
            for (int n = 0; n < 2; n++){
                bf16x8 bb = *reinterpret_cast<const bf16x8*>(WABs + (size_t)((kt*16 + nb7 + n)*64 + l)*8);
                ac[n] = mfma16(a, bb, ac[n]);
            }
        }
        #pragma unroll
        for (int n = 0; n < 2; n++){
            #pragma unroll
            for (int r = 0; r < 4; r++)
                A1[(drow+r)*260 + (nb7+n)*16 + dcol] = ac[n][r];
        }
    }
    __syncthreads();

    // ---- P8 (VALU): P = w2@A1 (K=32) -> bf16 P2 (over dead Xoa) + SP ----
    {
        float ap0[4], ap1[4];
        #pragma unroll
        for (int u=0;u<4;u++){ ap0[u]=0.f; ap1[u]=0.f; }
        #pragma unroll
        for (int k0=0;k0<32;k0+=4){
            float4 xv[4];
            #pragma unroll
            for (int u=0;u<4;u++) xv[u] = ld4(Wb2f + (g*4+u)*36 + k0);
            #pragma unroll
            for (int kk=0;kk<4;kk++){
                float2 w = *reinterpret_cast<const float2*>(A1 + (k0+kk)*260 + cp);
                #pragma unroll
                for (int u=0;u<4;u++){
                    float x = elem(xv[u],kk);
                    ap0[u] = fmaf(x, w.x, ap0[u]);
                    ap1[u] = fmaf(x, w.y, ap1[u]);
                }
            }
        }
        #pragma unroll
        for (int u=0;u<4;u++)
            P2[(g*4+u)*128 + (cp>>1)] = pack2(ap0[u], ap1[u]);
        float2 w2v = *reinterpret_cast<const float2*>(W2 + cp);
        float sp[4];
        #pragma unroll
        for (int u=0;u<4;u++) sp[u] = ap0[u]*w2v.x + ap1[u]*w2v.y;
        #pragma unroll
        for (int d=1; d<64; d<<=1){
            #pragma unroll
            for (int u=0;u<4;u++) sp[u] += __shfl_xor(sp[u], d);
        }
        if (l == 0){
            #pragma unroll
            for (int u=0;u<4;u++) SPQ[(g*4+u)*2 + wp] = sp[u];
        }
    }
    __syncthreads();

    // ---- P9 (VALU): Q = (pol-act)@WB -> bf16 Q2 (over dead A1) + SQ ----
    {
        float aq0[4], aq1[4];
        #pragma unroll
        for (int u=0;u<4;u++){ aq0[u]=0.f; aq1[u]=0.f; }
        const float* wB = WABf + 128*256;
        #pragma unroll
        for (int k0=0;k0<16;k0+=4){
            float4 xv[4];
            #pragma unroll
            for (int u=0;u<4;u++) xv[u] = ld4(APd + (g*4+u)*16 + k0);
            #pragma unroll
            for (int kk=0;kk<4;kk++){
                float2 w = *reinterpret_cast<const float2*>(wB + (k0+kk)*256 + cp);
                #pragma unroll
                for (int u=0;u<4;u++){
                    float x = elem(xv[u],kk);
                    aq0[u] = fmaf(x, w.x, aq0[u]);
                    aq1[u] = fmaf(x, w.y, aq1[u]);
                }
            }
        }
        #pragma unroll
        for (int u=0;u<4;u++)
            Q2[(g*4+u)*132 + (cp>>1)] = pack2(aq0[u], aq1[u]);
        float2 w2v = *reinterpret_cast<const float2*>(W2 + cp);
        float sq[4];
        #pragma unroll
        for (int u=0;u<4;u++) sq[u] = aq0[u]*w2v.x + aq1[u]*w2v.y;
        #pragma unroll
        for (int d=1; d<64; d<<=1){
            #pragma unroll
            for (int u=0;u<4;u++) sq[u] += __shfl_xor(sq[u], d);
        }
        if (l == 0){
            #pragma unroll
            for (int u=0;u<4;u++) SPQ[64 + (g*4+u)*2 + wp] = sq[u];
        }
    }
    __syncthreads();

    // ---- P10: value[i,j] = 0.505*(SP[i]+w*SQ[j]) + 0.495*sum_h W2[h]*|..| ----
    {
        float w00 = Wb2f[si*36 + sj];
        float SPi = SPQ[si*2] + SPQ[si*2+1];
        float SQa = SPQ[64 + sj*2] + SPQ[64 + sj*2+1];
        float a0 = 0.f;

        #define PROC(PA,QA,H2) {                                            \
            float w2e = W2[(H2)], w2o = W2[(H2)+1];                         \
            float paE = __uint_as_float((PA)<<16), paO = __uint_as_float((PA) & 0xffff0000u); \
            float qaE = __uint_as_float((QA)<<16), qaO = __uint_as_float((QA) & 0xffff0000u); \
            float t0 = fmaf(w00, qaE, paE); a0 = fmaf(fabsf(t0), w2e, a0);  \
            float t1 = fmaf(w00, qaO, paO); a0 = fmaf(fabsf(t1), w2o, a0); }

        #pragma unroll 4
        for (int hp4 = 0; hp4 < 32; hp4++){
            uint4 pa4 = *reinterpret_cast<const uint4*>(P2 + si*128 + hp4*4);
            uint4 qa4 = *reinterpret_cast<const uint4*>(Q2 + sj*132 + hp4*4);
            PROC(pa4.x, qa4.x, hp4*8+0)
            PROC(pa4.y, qa4.y, hp4*8+2)
            PROC(pa4.z, qa4.z, hp4*8+4)
            PROC(pa4.w, qa4.w, hp4*8+6)
        }
        #undef PROC

        out_v[(size_t)b*1024 + si*32 + sj] = fmaf(0.495f, a0, 0.505f*(SPi + w00*SQa));
    }
}

extern "C" void kernel_launch(void* const* d_in, const int* in_sizes, int n_in,
                              void* d_out, int out_size, void* d_ws, size_t ws_size,
                              hipStream_t stream) {
    const float* states = (const float*)d_in[0];
    const float* pol    = (const float*)d_in[1];
    const float* act    = (const float*)d_in[2];
    const float* Wkp    = (const float*)d_in[3];
    const float* Wqp    = (const float*)d_in[4];
    const float* Wvp    = (const float*)d_in[5];
    const float* Wk     = (const float*)d_in[6];
    const float* Wq     = (const float*)d_in[7];
    const float* We     = (const float*)d_in[8];
    const float* Wav    = (const float*)d_in[9];
    const float* W1     = (const float*)d_in[10];
    const float* W2     = (const float*)d_in[11];

    float* out    = (float*)d_out;
    float* out_v  = out;                 // [256,32,32,1]
    float* out_w1 = out + 256*1024;      // [256,32,32]
    float* out_w2 = out + 2*256*1024;    // [256,32,32]

    // workspace layout (floats)
    float* WABf = (float*)d_ws;                                  // [144][256] (rows 128..143 used)
    unsigned short* WABs = (unsigned short*)(WABf + 36864);      // 80 frags
    unsigned short* wsu  = (unsigned short*)(WABf + 57344);
    unsigned short* Wqps = wsu;             // 32 frags each
    unsigned short* Wkps = wsu + 16384;
    unsigned short* Wvqs = wsu + 32768;
    unsigned short* Wvks = wsu + 49152;

    hipLaunchKernelGGL(k_pre, dim3(40), dim3(512), 0, stream,
                       We, Wav, W1, Wqp, Wkp, Wvp, Wq, Wk,
                       WABf, WABs, Wqps, Wkps, Wvqs, Wvks);
    hipLaunchKernelGGL(k_main, dim3(NB), dim3(1024), 0, stream,
                       states, pol, act,
                       Wqps, Wkps, Wvqs, Wvks, WABs, WABf, W2,
                       out_v, out_w1, out_w2);
}

// Round 15
// 36.201 us; speedup vs baseline: 3.3396x; 1.0081x over previous
//
#include <hip/hip_runtime.h>
#include <math.h>

// Problem constants
#define NB 256   // batches
#define NN 32    // agents
#define DD 128   // state dim
#define NA 16    // action dim
#define HH 256   // hidden

using f32x4v  = __attribute__((ext_vector_type(4))) float;
using bf16x8  = __attribute__((ext_vector_type(8))) short;

static __device__ __forceinline__ float4 ld4(const float* p){ return *reinterpret_cast<const float4*>(p); }
static __device__ __forceinline__ void st4f(float* p, float4 v){ *reinterpret_cast<float4*>(p) = v; }
static __device__ __forceinline__ float elem(float4 v, int kk){
    return (kk==0)?v.x:(kk==1)?v.y:(kk==2)?v.z:v.w;
}

static __device__ __forceinline__ unsigned f2bf(float x){
    unsigned u = __float_as_uint(x);
    u += 0x7fffu + ((u >> 16) & 1u);   // round-to-nearest-even
    return u >> 16;
}
static __device__ __forceinline__ unsigned pack2(float a, float b){
    return f2bf(a) | (f2bf(b) << 16);
}

static __device__ __forceinline__ f32x4v mfma16(bf16x8 a, bf16x8 b, f32x4v c){
    return __builtin_amdgcn_mfma_f32_16x16x32_bf16(a, b, c, 0, 0, 0);
}

static __device__ __forceinline__ bf16x8 to_bf8(const float v[8]){
    union { bf16x8 v8; unsigned u[4]; } r;
    #pragma unroll
    for (int j = 0; j < 4; j++) r.u[j] = pack2(v[2*j], v[2*j+1]);
    return r.v8;
}

// write one B-fragment (16 bf16 bytes per lane) to the swizzled weight buffer
static __device__ __forceinline__ void store_frag(unsigned short* __restrict__ dst,
                                                  int frag, int l, const float v[8]){
    uint4 p;
    p.x = pack2(v[0], v[1]); p.y = pack2(v[2], v[3]);
    p.z = pack2(v[4], v[5]); p.w = pack2(v[6], v[7]);
    *reinterpret_cast<uint4*>(dst + (size_t)(frag*64 + l)*8) = p;
}

// =============================================================================
// k_pre (40 blocks x 512), MFMA-based (identical to R13/R14):
//   0..15 : WAB col-tile (2-stage MFMA) -> WABs frags + WABf rows 128..143
//   16..23: Wqp/Wkp fragment swizzles
//   24..31: Wvq = Wvp@Wq col-tile -> Wvqs frags
//   32..39: Wvk = Wvp@Wk col-tile -> Wvks frags
// =============================================================================
__global__ __launch_bounds__(512)
void k_pre(const float* __restrict__ We, const float* __restrict__ Wav,
           const float* __restrict__ W1,
           const float* __restrict__ Wqp, const float* __restrict__ Wkp,
           const float* __restrict__ Wvp, const float* __restrict__ Wq,
           const float* __restrict__ Wk,
           float* __restrict__ WABf, unsigned short* __restrict__ WABs,
           unsigned short* __restrict__ Wqps, unsigned short* __restrict__ Wkps,
           unsigned short* __restrict__ Wvqs, unsigned short* __restrict__ Wvks)
{
    __shared__ float SH[5120];
    const int t = threadIdx.x;
    const int bid = blockIdx.x;
    const int l   = t & 63;
    const int wvv = t >> 6;
    const int lg  = l >> 4;
    const int lc  = l & 15;

    if (bid < 16) {
        float* T2f  = SH;          // [128][20]
        float* WABt = SH + 2560;   // [160][16]
        const int ct = bid;
        {
            const int arow = wvv*16 + lc;
            f32x4v acc = {0.f,0.f,0.f,0.f};
            #pragma unroll
            for (int kt = 0; kt < 4; kt++) {
                const float* ap = Wav + (size_t)arow*128 + kt*32 + lg*8;
                float4 a0 = ld4(ap), a1 = ld4(ap + 4);
                float av8[8] = {a0.x,a0.y,a0.z,a0.w,a1.x,a1.y,a1.z,a1.w};
                const float* bp = W1 + (size_t)(kt*32 + lg*8)*256 + ct*16 + lc;
                float bv8[8];
                #pragma unroll
                for (int i = 0; i < 8; i++) bv8[i] = bp[(size_t)i*256];
                acc = mfma16(to_bf8(av8), to_bf8(bv8), acc);
            }
            const int dr = wvv*16 + lg*4;
            #pragma unroll
            for (int r = 0; r < 4; r++) T2f[(dr+r)*20 + lc] = acc[r];
        }
        __syncthreads();
        #pragma unroll
        for (int pass = 0; pass < 2; pass++) {
            const int mt9 = (pass == 0) ? wvv : 8 + wvv;
            if (pass == 1 && wvv >= 2) continue;
            const int arow = mt9*16 + lc;
            f32x4v acc = {0.f,0.f,0.f,0.f};
            #pragma unroll
            for (int kt = 0; kt < 4; kt++) {
                float av8[8];
                if (arow < 144) {
                    const float* ap = We + (size_t)arow*128 + kt*32 + lg*8;
                    float4 a0 = ld4(ap), a1 = ld4(ap + 4);
                    av8[0]=a0.x; av8[1]=a0.y; av8[2]=a0.z; av8[3]=a0.w;
                    av8[4]=a1.x; av8[5]=a1.y; av8[6]=a1.z; av8[7]=a1.w;
                } else {
                    #pragma unroll
                    for (int i = 0; i < 8; i++) av8[i] = 0.f;
                }
                float bv8[8];
                #pragma unroll
                for (int i = 0; i < 8; i++) bv8[i] = T2f[(kt*32 + lg*8 + i)*20 + lc];
                acc = mfma16(to_bf8(av8), to_bf8(bv8), acc);
            }
            const int dr = mt9*16 + lg*4;
            #pragma unroll
            for (int r = 0; r < 4; r++) WABt[(dr+r)*16 + lc] = acc[r];
            if (mt9 == 8) {
                #pragma unroll
                for (int r = 0; r < 4; r++)
                    WABf[(size_t)(dr+r)*256 + ct*16 + lc] = acc[r];
            }
        }
        __syncthreads();
        if (t < 320) {
            int kt = t >> 6, ll = t & 63;
            float v[8];
            #pragma unroll
            for (int i = 0; i < 8; i++)
                v[i] = WABt[(kt*32 + (ll>>4)*8 + i)*16 + (ll&15)];
            store_frag(WABs, kt*16 + ct, ll, v);
        }
    } else if (bid < 24) {
        const int bb = bid - 16;
        const int fg = bb*8 + (t >> 6);
        const int sel = fg >> 5, frag = fg & 31;
        const int kt = frag >> 3, nt = frag & 7;
        const float* W = (sel==0) ? Wqp : Wkp;
        unsigned short* dst = (sel==0) ? Wqps : Wkps;
        float v[8];
        #pragma unroll
        for (int i = 0; i < 8; i++)
            v[i] = W[(kt*32 + (l>>4)*8 + i)*128 + nt*16 + (l&15)];
        store_frag(dst, frag, l, v);
    } else {
        float* T2f = SH;    // [128][20]
        const int ct = (bid - 24) & 7;
        const float* Bsrc = (bid < 32) ? Wq : Wk;
        unsigned short* dst = (bid < 32) ? Wvqs : Wvks;
        {
            const int arow = wvv*16 + lc;
            f32x4v acc = {0.f,0.f,0.f,0.f};
            #pragma unroll
            for (int kt = 0; kt < 4; kt++) {
                const float* ap = Wvp + (size_t)arow*128 + kt*32 + lg*8;
                float4 a0 = ld4(ap), a1 = ld4(ap + 4);
                float av8[8] = {a0.x,a0.y,a0.z,a0.w,a1.x,a1.y,a1.z,a1.w};
                const float* bp = Bsrc + (size_t)(kt*32 + lg*8)*128 + ct*16 + lc;
                float bv8[8];
                #pragma unroll
                for (int i = 0; i < 8; i++) bv8[i] = bp[(size_t)i*128];
                acc = mfma16(to_bf8(av8), to_bf8(bv8), acc);
            }
            const int dr = wvv*16 + lg*4;
            #pragma unroll
            for (int r = 0; r < 4; r++) T2f[(dr+r)*20 + lc] = acc[r];
        }
        __syncthreads();
        if (t < 256) {
            int kt = t >> 6, ll = t & 63;
            float v[8];
            #pragma unroll
            for (int i = 0; i < 8; i++)
                v[i] = T2f[(kt*32 + (ll>>4)*8 + i)*20 + (ll&15)];
            store_frag(dst, kt*8 + ct, ll, v);
        }
    }
}

// scores+softmax, 1024 threads: thread (i=t>>5, j=t&31) covers one (i,j).
static __device__ __forceinline__ void scores_softmax1024(const float* __restrict__ Qm,
                                                          const float* __restrict__ Km,
                                                          float scale,
                                                          float* __restrict__ w_lds,
                                                          float* __restrict__ w_out,
                                                          int i, int j)
{
    float s0 = 0.f;
    #pragma unroll 4
    for (int k=0;k<128;k+=4){
        float4 qv = ld4(Qm + i*132 + k);
        float4 k0 = ld4(Km + j*132 + k);
        s0 += qv.x*k0.x + qv.y*k0.y + qv.z*k0.z + qv.w*k0.w;
    }
    s0 *= scale;
    float m = s0;
    #pragma unroll
    for (int d=1; d<32; d<<=1) m = fmaxf(m, __shfl_xor(m, d));
    float e0 = expf(s0 - m);
    float sum = e0;
    #pragma unroll
    for (int d=1; d<32; d<<=1) sum += __shfl_xor(sum, d);
    float w = e0 / sum;
    w_lds[i*36 + j] = w;
    w_out[i*32 + j] = w;
}

// =============================================================================
// k_main: one block per batch, 1024 threads (16 waves/CU). Hoisted schedule:
//   stage -> Q-calc (VALU regs, overlaps) -> P1+A1 (MFMA, A1 in regs) -> sm1
//   -> svqk store -> P3' -> sm2 -> A1 store -> P8 (P+SP) -> Q2 store (+SQ)
//   -> P10.
// =============================================================================
__global__ __launch_bounds__(1024)
void k_main(const float* __restrict__ states, const float* __restrict__ pol,
            const float* __restrict__ act,
            const unsigned short* __restrict__ Wqps, const unsigned short* __restrict__ Wkps,
            const unsigned short* __restrict__ Wvqs, const unsigned short* __restrict__ Wvks,
            const unsigned short* __restrict__ WABs, const float* __restrict__ WABf,
            const float* __restrict__ W2,
            float* __restrict__ out_v, float* __restrict__ out_w1,
            float* __restrict__ out_w2)
{
    const int b = blockIdx.x;
    const int t = threadIdx.x;
    const float scale = 0.08838834764831845f;  // 1/sqrt(128)

    __shared__ float SH[15360];   // 60 KB
    float* B1   = SH;                                     // [32][132]
    float* B2   = SH + 4224;                              // [32][132]
    float* Wb1f = SH + 8448;                              // [32][36]
    float* Wb2f = SH + 9600;                              // [32][36]
    float* APd  = SH + 10752;                             // [32][16]
    unsigned short* Xoa = (unsigned short*)(SH + 11264);  // [32][168] bf16
    float*    A1 = SH;                                    // [32][260] over B1+B2
    unsigned* P2 = (unsigned*)(SH + 11264);               // [32][128] over dead Xoa
    unsigned* Q2 = (unsigned*)SH;                         // [32][132] over dead A1
    float* SPQ = Wb1f;                                    // SP/SQ over dead Wb1f

    const float* stg  = states + (size_t)b*(NN*DD);
    const float* actg = act + (size_t)b*(NN*NA);
    const float* polg = pol + (size_t)b*(NN*NA);

    const int l   = t & 63;
    const int wvv = t >> 6;   // 0..15
    const int lg  = l >> 4;
    const int lc  = l & 15;

    // ---- stage Xoa = bf16([st | act | 0]), APd = pol-act ----
    {
        int r = t >> 5, kb = t & 31;
        #pragma unroll
        for (int uu = 0; uu < 5; uu++){
            int k = kb + 32*uu;
            float v = (k < 128) ? stg[r*128 + k]
                    : (k < 144) ? actg[r*16 + (k-128)] : 0.f;
            Xoa[r*168 + k] = (unsigned short)f2bf(v);
        }
        if (t < 128) {
            int rr = t>>2, cc = (t&3)*4;
            float4 p = ld4(polg + rr*16 + cc), a = ld4(actg + rr*16 + cc);
            st4f(APd + rr*16 + cc, make_float4(p.x-a.x, p.y-a.y, p.z-a.z, p.w-a.w));
        }
    }
    __syncthreads();

    // geometry (16 waves)
    const int mt   = wvv & 1;
    const int ntb  = wvv >> 1;            // 128-col GEMM N-tile: 0..7
    const int nb7  = (wvv >> 1) * 2;      // 256-col GEMM N-tile base
    const int arow = mt*16 + lc;
    const int drow = mt*16 + (lg << 2);
    const int dcol = lc;
    const int c  = t & 127;
    const int g  = t >> 7;                // 0..7 -> rows g*4..g*4+3
    const int cp = (t & 127)*2;
    const int si = t >> 5;
    const int sj = t & 31;
    const int wp = wvv & 1;

    // ---- Q-hoist (VALU): Q = (pol-act)@WB (K=16) -> regs + SQ butterfly ----
    float qr0[4], qr1[4], sq[4];
    {
        #pragma unroll
        for (int u=0;u<4;u++){ qr0[u]=0.f; qr1[u]=0.f; }
        const float* wB = WABf + 128*256;
        #pragma unroll
        for (int k0=0;k0<16;k0+=4){
            float4 xv[4];
            #pragma unroll
            for (int u=0;u<4;u++) xv[u] = ld4(APd + (g*4+u)*16 + k0);
            #pragma unroll
            for (int kk=0;kk<4;kk++){
                float2 w = *reinterpret_cast<const float2*>(wB + (k0+kk)*256 + cp);
                #pragma unroll
                for (int u=0;u<4;u++){
                    float x = elem(xv[u],kk);
                    qr0[u] = fmaf(x, w.x, qr0[u]);
                    qr1[u] = fmaf(x, w.y, qr1[u]);
                }
            }
        }
        float2 w2v = *reinterpret_cast<const float2*>(W2 + cp);
        #pragma unroll
        for (int u=0;u<4;u++) sq[u] = qr0[u]*w2v.x + qr1[u]*w2v.y;
        #pragma unroll
        for (int d=1; d<64; d<<=1){
            #pragma unroll
            for (int u=0;u<4;u++) sq[u] += __shfl_xor(sq[u], d);
        }
    }

    // ---- P1 (MFMA x4): q1->B1, k1->B2, svq/svk -> regs ----
    f32x4v asq0={0.f,0.f,0.f,0.f};
    f32x4v ask0={0.f,0.f,0.f,0.f};
    {
        f32x4v aq0={0.f,0.f,0.f,0.f};
        f32x4v ak0={0.f,0.f,0.f,0.f};
        const unsigned short* ab = Xoa + arow*168 + lg*8;
        #pragma unroll
        for (int kt = 0; kt < 4; kt++){
            bf16x8 a = *reinterpret_cast<const bf16x8*>(ab + kt*32);
            bf16x8 bq0 = *reinterpret_cast<const bf16x8*>(Wqps + (size_t)((kt*8+ntb)*64 + l)*8);
            bf16x8 bk0 = *reinterpret_cast<const bf16x8*>(Wkps + (size_t)((kt*8+ntb)*64 + l)*8);
            bf16x8 bv0 = *reinterpret_cast<const bf16x8*>(Wvqs + (size_t)((kt*8+ntb)*64 + l)*8);
            bf16x8 bw0 = *reinterpret_cast<const bf16x8*>(Wvks + (size_t)((kt*8+ntb)*64 + l)*8);
            aq0 = mfma16(a, bq0, aq0);
            ak0 = mfma16(a, bk0, ak0);
            asq0 = mfma16(a, bv0, asq0);
            ask0 = mfma16(a, bw0, ask0);
        }
        #pragma unroll
        for (int r = 0; r < 4; r++){
            B1[(drow+r)*132 + ntb*16 + dcol] = aq0[r];
            B2[(drow+r)*132 + ntb*16 + dcol] = ak0[r];
        }
    }

    // ---- A1-hoist (MFMA): ac = [st|act|0]@WAB (K=160), regs until post-sm2 ----
    f32x4v ac[2];
    {
        #pragma unroll
        for (int n=0;n<2;n++) ac[n] = f32x4v{0.f,0.f,0.f,0.f};
        const unsigned short* ab = Xoa + arow*168 + lg*8;
        #pragma unroll
        for (int kt = 0; kt < 5; kt++){
            bf16x8 a = *reinterpret_cast<const bf16x8*>(ab + kt*32);
            #pragma unroll
            for (int n = 0; n < 2; n++){
                bf16x8 bb = *reinterpret_cast<const bf16x8*>(WABs + (size_t)((kt*16 + nb7 + n)*64 + l)*8);
                ac[n] = mfma16(a, bb, ac[n]);
            }
        }
    }
    __syncthreads();

    // ---- sm1: w1 = softmax(q1@k1^T * scale) ----
    scores_softmax1024(B1, B2, scale, Wb1f, out_w1 + (size_t)b*1024, si, sj);
    __syncthreads();

    // ---- store svq/svk over dead q1/k1 ----
    #pragma unroll
    for (int r = 0; r < 4; r++){
        B1[(drow+r)*132 + ntb*16 + dcol] = asq0[r];
        B2[(drow+r)*132 + ntb*16 + dcol] = ask0[r];
    }
    __syncthreads();

    // ---- P3': q2 = w1@SVQ, k2 = w1@SVK (VALU K=32) -> regs -> B1,B2 ----
    {
        float q2a[4], k2a[4];
        #pragma unroll
        for (int u=0;u<4;u++){ q2a[u]=0.f; k2a[u]=0.f; }
        #pragma unroll
        for (int k0=0;k0<32;k0+=4){
            float4 xv[4];
            #pragma unroll
            for (int u=0;u<4;u++) xv[u] = ld4(Wb1f + (g*4+u)*36 + k0);
            #pragma unroll
            for (int kk=0;kk<4;kk++){
                float vq = B1[(k0+kk)*132 + c];
                float vk = B2[(k0+kk)*132 + c];
                #pragma unroll
                for (int u=0;u<4;u++){
                    float x = elem(xv[u],kk);
                    q2a[u] = fmaf(x, vq, q2a[u]);
                    k2a[u] = fmaf(x, vk, k2a[u]);
                }
            }
        }
        __syncthreads();   // SVQ/SVK reads done
        #pragma unroll
        for (int u=0;u<4;u++){
            B1[(g*4+u)*132 + c] = q2a[u];
            B2[(g*4+u)*132 + c] = k2a[u];
        }
    }
    __syncthreads();

    // ---- sm2: w2 = softmax(q2@k2^T * scale) ----
    scores_softmax1024(B1, B2, scale, Wb2f, out_w2 + (size_t)b*1024, si, sj);
    __syncthreads();

    // ---- A1 store (over dead B1/B2) ----
    #pragma unroll
    for (int n = 0; n < 2; n++){
        #pragma unroll
        for (int r = 0; r < 4; r++)
            A1[(drow+r)*260 + (nb7+n)*16 + dcol] = ac[n][r];
    }
    __syncthreads();

    // ---- P8 (VALU): P = w2@A1 (K=32) -> bf16 P2 (over dead Xoa) + SP ----
    {
        float ap0[4], ap1[4];
        #pragma unroll
        for (int u=0;u<4;u++){ ap0[u]=0.f; ap1[u]=0.f; }
        #pragma unroll
        for (int k0=0;k0<32;k0+=4){
            float4 xv[4];
            #pragma unroll
            for (int u=0;u<4;u++) xv[u] = ld4(Wb2f + (g*4+u)*36 + k0);
            #pragma unroll
            for (int kk=0;kk<4;kk++){
                float2 w = *reinterpret_cast<const float2*>(A1 + (k0+kk)*260 + cp);
                #pragma unroll
                for (int u=0;u<4;u++){
                    float x = elem(xv[u],kk);
                    ap0[u] = fmaf(x, w.x, ap0[u]);
                    ap1[u] = fmaf(x, w.y, ap1[u]);
                }
            }
        }
        #pragma unroll
        for (int u=0;u<4;u++)
            P2[(g*4+u)*128 + (cp>>1)] = pack2(ap0[u], ap1[u]);
        float2 w2v = *reinterpret_cast<const float2*>(W2 + cp);
        float sp[4];
        #pragma unroll
        for (int u=0;u<4;u++) sp[u] = ap0[u]*w2v.x + ap1[u]*w2v.y;
        #pragma unroll
        for (int d=1; d<64; d<<=1){
            #pragma unroll
            for (int u=0;u<4;u++) sp[u] += __shfl_xor(sp[u], d);
        }
        if (l == 0){
            #pragma unroll
            for (int u=0;u<4;u++) SPQ[(g*4+u)*2 + wp] = sp[u];
        }
    }
    __syncthreads();

    // ---- Q2 store (over dead A1) + SQ partials ----
    {
        #pragma unroll
        for (int u=0;u<4;u++)
            Q2[(g*4+u)*132 + (cp>>1)] = pack2(qr0[u], qr1[u]);
        if (l == 0){
            #pragma unroll
            for (int u=0;u<4;u++) SPQ[64 + (g*4+u)*2 + wp] = sq[u];
        }
    }
    __syncthreads();

    // ---- P10: value[i,j] = 0.505*(SP[i]+w*SQ[j]) + 0.495*sum_h W2[h]*|..| ----
    {
        float w00 = Wb2f[si*36 + sj];
        float SPi = SPQ[si*2] + SPQ[si*2+1];
        float SQa = SPQ[64 + sj*2] + SPQ[64 + sj*2+1];
        float a0 = 0.f;

        #define PROC(PA,QA,H2) {                                            \
            float w2e = W2[(H2)], w2o = W2[(H2)+1];                         \
            float paE = __uint_as_float((PA)<<16), paO = __uint_as_float((PA) & 0xffff0000u); \
            float qaE = __uint_as_float((QA)<<16), qaO = __uint_as_float((QA) & 0xffff0000u); \
            float t0 = fmaf(w00, qaE, paE); a0 = fmaf(fabsf(t0), w2e, a0);  \
            float t1 = fmaf(w00, qaO, paO); a0 = fmaf(fabsf(t1), w2o, a0); }

        #pragma unroll 4
        for (int hp4 = 0; hp4 < 32; hp4++){
            uint4 pa4 = *reinterpret_cast<const uint4*>(P2 + si*128 + hp4*4);
            uint4 qa4 = *reinterpret_cast<const uint4*>(Q2 + sj*132 + hp4*4);
            PROC(pa4.x, qa4.x, hp4*8+0)
            PROC(pa4.y, qa4.y, hp4*8+2)
            PROC(pa4.z, qa4.z, hp4*8+4)
            PROC(pa4.w, qa4.w, hp4*8+6)
        }
        #undef PROC

        out_v[(size_t)b*1024 + si*32 + sj] = fmaf(0.495f, a0, 0.505f*(SPi + w00*SQa));
    }
}

extern "C" void kernel_launch(void* const* d_in, const int* in_sizes, int n_in,
                              void* d_out, int out_size, void* d_ws, size_t ws_size,
                              hipStream_t stream) {
    const float* states = (const float*)d_in[0];
    const float* pol    = (const float*)d_in[1];
    const float* act    = (const float*)d_in[2];
    const float* Wkp    = (const float*)d_in[3];
    const float* Wqp    = (const float*)d_in[4];
    const float* Wvp    = (const float*)d_in[5];
    const float* Wk     = (const float*)d_in[6];
    const float* Wq     = (const float*)d_in[7];
    const float* We     = (const float*)d_in[8];
    const float* Wav    = (const float*)d_in[9];
    const float* W1     = (const float*)d_in[10];
    const float* W2     = (const float*)d_in[11];

    float* out    = (float*)d_out;
    float* out_v  = out;                 // [256,32,32,1]
    float* out_w1 = out + 256*1024;      // [256,32,32]
    float* out_w2 = out + 2*256*1024;    // [256,32,32]

    // workspace layout (floats)
    float* WABf = (float*)d_ws;                                  // [144][256] (rows 128..143 used)
    unsigned short* WABs = (unsigned short*)(WABf + 36864);      // 80 frags
    unsigned short* wsu  = (unsigned short*)(WABf + 57344);
    unsigned short* Wqps = wsu;             // 32 frags each
    unsigned short* Wkps = wsu + 16384;
    unsigned short* Wvqs = wsu + 32768;
    unsigned short* Wvks = wsu + 49152;

    hipLaunchKernelGGL(k_pre, dim3(40), dim3(512), 0, stream,
                       We, Wav, W1, Wqp, Wkp, Wvp, Wq, Wk,
                       WABf, WABs, Wqps, Wkps, Wvqs, Wvks);
    hipLaunchKernelGGL(k_main, dim3(NB), dim3(1024), 0, stream,
                       states, pol, act,
                       Wqps, Wkps, Wvqs, Wvks, WABs, WABf, W2,
                       out_v, out_w1, out_w2);
}